// Round 1
// baseline (2378.490 us; speedup 1.0000x reference)
//
#include <hip/hip_runtime.h>

// ---------------------------------------------------------------------------
// GIN: 10 rounds of (h + scatter_add(h[src] -> dst)) interleaved with small
// MLPs. Strategy: build CSR (incoming edges grouped by dst) once per launch,
// then each aggregation is a pull-gather (no float atomics, coalesced reads).
// State h [N,32] f32 ping-pongs between two ws buffers (fits L3/L2).
// ---------------------------------------------------------------------------

static __device__ __forceinline__ float selu_f(float x) {
    const float scale = 1.0507009873554805f;
    const float alpha = 1.6732632423543772f;
    return x > 0.f ? scale * x : scale * alpha * (__expf(x) - 1.f);
}

// ---- CSR build -------------------------------------------------------------

__global__ void k_count(const int* __restrict__ dst, int* __restrict__ cnt, int e) {
    int i = blockIdx.x * blockDim.x + threadIdx.x;
    if (i < e) atomicAdd(&cnt[dst[i]], 1);
}

// exclusive scan, phase 1: per-1024-chunk scan (256 thr x 4 items)
__global__ void k_scan1(const int* __restrict__ cnt, int* __restrict__ rp,
                        int* __restrict__ bsum, int n) {
    int tb = blockIdx.x * 1024 + threadIdx.x * 4;
    int c0 = (tb + 0 < n) ? cnt[tb + 0] : 0;
    int c1 = (tb + 1 < n) ? cnt[tb + 1] : 0;
    int c2 = (tb + 2 < n) ? cnt[tb + 2] : 0;
    int c3 = (tb + 3 < n) ? cnt[tb + 3] : 0;
    int t = c0 + c1 + c2 + c3;
    int lane = threadIdx.x & 63, wave = threadIdx.x >> 6;
    int inc = t;
    #pragma unroll
    for (int d = 1; d < 64; d <<= 1) {
        int v = __shfl_up(inc, d, 64);
        if (lane >= d) inc += v;
    }
    __shared__ int wtot[4];
    if (lane == 63) wtot[wave] = inc;
    __syncthreads();
    int woff = 0;
    #pragma unroll
    for (int w = 0; w < 4; ++w)
        if (w < wave) woff += wtot[w];
    int excl = woff + inc - t;  // exclusive prefix of this thread's 4 items
    if (tb + 0 < n) rp[tb + 0] = excl;
    if (tb + 1 < n) rp[tb + 1] = excl + c0;
    if (tb + 2 < n) rp[tb + 2] = excl + c0 + c1;
    if (tb + 3 < n) rp[tb + 3] = excl + c0 + c1 + c2;
    if (threadIdx.x == 255) bsum[blockIdx.x] = woff + inc;  // block total
}

// phase 2: exclusive scan of block sums (nb <= 256), single block
__global__ void k_scan2(int* bsum, int nb) {
    __shared__ int s[256];
    int t = (threadIdx.x < nb) ? bsum[threadIdx.x] : 0;
    s[threadIdx.x] = t;
    __syncthreads();
    #pragma unroll
    for (int d = 1; d < 256; d <<= 1) {
        int v = (threadIdx.x >= (unsigned)d) ? s[threadIdx.x - d] : 0;
        __syncthreads();
        s[threadIdx.x] += v;
        __syncthreads();
    }
    if (threadIdx.x < nb) bsum[threadIdx.x] = s[threadIdx.x] - t;  // exclusive
}

// phase 3: add block offsets; also init fill cursor and rp[n]=e
__global__ void k_scan3(int* __restrict__ rp, int* __restrict__ cur,
                        const int* __restrict__ bsum, int n, int e) {
    int i = blockIdx.x * blockDim.x + threadIdx.x;
    if (i < n) {
        int v = rp[i] + bsum[i >> 10];
        rp[i] = v;
        cur[i] = v;
    }
    if (i == 0) rp[n] = e;
}

__global__ void k_fill(const int* __restrict__ src, const int* __restrict__ dst,
                       int* cur, int* __restrict__ esrc, int e) {
    int i = blockIdx.x * blockDim.x + threadIdx.x;
    if (i < e) {
        int d = dst[i];
        int p = atomicAdd(&cur[d], 1);
        esrc[p] = src[i];
    }
}

// ---- aggregation (pull-gather) ---------------------------------------------

// C=1 aggregation for block 0: one thread per node
__global__ void k_agg1(const float* __restrict__ x, const int* __restrict__ rp,
                       const int* __restrict__ esrc, float* __restrict__ agg, int n) {
    int i = blockIdx.x * blockDim.x + threadIdx.x;
    if (i >= n) return;
    float a = x[i];
    int b = rp[i], en = rp[i + 1];
    for (int j = b; j < en; ++j) a += x[esrc[j]];
    agg[i] = a;
}

// C=32 aggregation: 32 lanes per node (lane = channel); each edge iteration
// reads one contiguous 128B line of h[src].
__global__ void k_agg32(const float* __restrict__ h, const int* __restrict__ rp,
                        const int* __restrict__ esrc, float* __restrict__ out, int n) {
    int gid = blockIdx.x * blockDim.x + threadIdx.x;
    int node = gid >> 5;
    int c = gid & 31;
    if (node >= n) return;
    float acc = h[(size_t)node * 32 + c];
    int b = rp[node], en = rp[node + 1];
    for (int j = b; j < en; ++j) {
        int s = esrc[j];
        acc += h[(size_t)s * 32 + c];
    }
    out[(size_t)node * 32 + c] = acc;
}

// ---- MLPs -------------------------------------------------------------------

// block 0 MLP: [1 -> 16(selu) -> 32], one thread per node
__global__ void k_mlp0(const float* __restrict__ agg, const float* __restrict__ W1,
                       const float* __restrict__ b1, const float* __restrict__ W2,
                       const float* __restrict__ b2, float* __restrict__ h, int n) {
    __shared__ float sW1[16], sb1[16], sW2[512], sb2[32];
    if (threadIdx.x < 16) { sW1[threadIdx.x] = W1[threadIdx.x]; sb1[threadIdx.x] = b1[threadIdx.x]; }
    for (int t = threadIdx.x; t < 512; t += 256) sW2[t] = W2[t];
    if (threadIdx.x < 32) sb2[threadIdx.x] = b2[threadIdx.x];
    __syncthreads();
    int i = blockIdx.x * blockDim.x + threadIdx.x;
    if (i >= n) return;
    float a = agg[i];
    float u[16];
    #pragma unroll
    for (int k = 0; k < 16; ++k) u[k] = selu_f(fmaf(a, sW1[k], sb1[k]));
    float4* op = (float4*)(h + (size_t)i * 32);
    #pragma unroll
    for (int q = 0; q < 8; ++q) {
        float o[4];
        #pragma unroll
        for (int jj = 0; jj < 4; ++jj) {
            int j = q * 4 + jj;
            float acc = sb2[j];
            #pragma unroll
            for (int k = 0; k < 16; ++k) acc = fmaf(u[k], sW2[k * 32 + j], acc);
            o[jj] = acc;
        }
        op[q] = make_float4(o[0], o[1], o[2], o[3]);
    }
}

// mid MLP: [32 -> 16(selu) -> 32] + residual; reads agg row fully into regs,
// then writes result back in place (out may alias agg; dataflow serializes).
__global__ void k_mlp_mid(const float* agg, const float* __restrict__ res,
                          const float* __restrict__ W1, const float* __restrict__ b1,
                          const float* __restrict__ W2, const float* __restrict__ b2,
                          float* out, int n) {
    __shared__ float sW1[512], sW2[512], sb1[16], sb2[32];
    for (int t = threadIdx.x; t < 512; t += 256) { sW1[t] = W1[t]; sW2[t] = W2[t]; }
    if (threadIdx.x < 16) sb1[threadIdx.x] = b1[threadIdx.x];
    if (threadIdx.x < 32) sb2[threadIdx.x] = b2[threadIdx.x];
    __syncthreads();
    int i = blockIdx.x * blockDim.x + threadIdx.x;
    if (i >= n) return;
    const float4* vp = (const float4*)(agg + (size_t)i * 32);
    float v[32];
    #pragma unroll
    for (int q = 0; q < 8; ++q) {
        float4 f = vp[q];
        v[q * 4 + 0] = f.x; v[q * 4 + 1] = f.y; v[q * 4 + 2] = f.z; v[q * 4 + 3] = f.w;
    }
    float u[16];
    #pragma unroll
    for (int k = 0; k < 16; ++k) u[k] = sb1[k];
    #pragma unroll
    for (int c = 0; c < 32; ++c) {
        float vc = v[c];
        #pragma unroll
        for (int k = 0; k < 16; ++k) u[k] = fmaf(vc, sW1[c * 16 + k], u[k]);
    }
    #pragma unroll
    for (int k = 0; k < 16; ++k) u[k] = selu_f(u[k]);
    const float4* rp4 = (const float4*)(res + (size_t)i * 32);
    float4* op = (float4*)(out + (size_t)i * 32);
    #pragma unroll
    for (int q = 0; q < 8; ++q) {
        float4 r = rp4[q];
        float o[4];
        #pragma unroll
        for (int jj = 0; jj < 4; ++jj) {
            int j = q * 4 + jj;
            float acc = sb2[j];
            #pragma unroll
            for (int k = 0; k < 16; ++k) acc = fmaf(u[k], sW2[k * 32 + j], acc);
            o[jj] = acc;
        }
        op[q] = make_float4(o[0] + r.x, o[1] + r.y, o[2] + r.z, o[3] + r.w);
    }
}

// final Linear(32 -> 1, no bias): one thread per node
__global__ void k_last(const float* __restrict__ agg, const float* __restrict__ W,
                       float* __restrict__ out, int n) {
    __shared__ float sW[32];
    if (threadIdx.x < 32) sW[threadIdx.x] = W[threadIdx.x];
    __syncthreads();
    int i = blockIdx.x * blockDim.x + threadIdx.x;
    if (i >= n) return;
    const float4* vp = (const float4*)(agg + (size_t)i * 32);
    float acc = 0.f;
    #pragma unroll
    for (int q = 0; q < 8; ++q) {
        float4 f = vp[q];
        acc += f.x * sW[q * 4 + 0] + f.y * sW[q * 4 + 1] +
               f.z * sW[q * 4 + 2] + f.w * sW[q * 4 + 3];
    }
    out[i] = acc;
}

// ---------------------------------------------------------------------------

extern "C" void kernel_launch(void* const* d_in, const int* in_sizes, int n_in,
                              void* d_out, int out_size, void* d_ws, size_t ws_size,
                              hipStream_t stream) {
    const float* x    = (const float*)d_in[0];
    const int*   ei   = (const int*)d_in[1];
    const float* W1_0 = (const float*)d_in[2];
    const float* b1_0 = (const float*)d_in[3];
    const float* W2_0 = (const float*)d_in[4];
    const float* b2_0 = (const float*)d_in[5];
    const float* W1m  = (const float*)d_in[6];
    const float* b1m  = (const float*)d_in[7];
    const float* W2m  = (const float*)d_in[8];
    const float* b2m  = (const float*)d_in[9];
    const float* Wl   = (const float*)d_in[10];

    const int n = in_sizes[0];      // 100000 nodes
    const int e = in_sizes[1] / 2;  // 1.6M edges
    const int* src  = ei;           // edge_index[0]
    const int* dstp = ei + e;       // edge_index[1]

    char* ws = (char*)d_ws;
    size_t off = 0;
    auto alloc = [&](size_t bytes) -> char* {
        char* p = ws + off;
        off += (bytes + 255) & ~size_t(255);
        return p;
    };
    float* hP   = (float*)alloc((size_t)n * 32 * 4);
    float* hQ   = (float*)alloc((size_t)n * 32 * 4);
    int*   rp   = (int*)alloc((size_t)(n + 1) * 4);
    int*   cur  = (int*)alloc((size_t)n * 4);
    int*   cnt  = (int*)alloc((size_t)n * 4);
    int*   esrc = (int*)alloc((size_t)e * 4);
    int*   bsum = (int*)alloc(4096);
    float* agg0 = (float*)alloc((size_t)n * 4);
    (void)ws_size;

    const int B = 256;
    const int gE = (e + B - 1) / B;
    const int gN = (n + B - 1) / B;
    const int nb = (n + 1023) / 1024;              // scan chunks (98 for N=100K)
    const int gA = (int)(((size_t)n * 32 + B - 1) / B);

    // --- CSR build (once per launch) ---
    hipMemsetAsync(cnt, 0, (size_t)n * 4, stream);
    k_count<<<gE, B, 0, stream>>>(dstp, cnt, e);
    k_scan1<<<nb, B, 0, stream>>>(cnt, rp, bsum, n);
    k_scan2<<<1, 256, 0, stream>>>(bsum, nb);
    k_scan3<<<gN, B, 0, stream>>>(rp, cur, bsum, n, e);
    k_fill<<<gE, B, 0, stream>>>(src, dstp, cur, esrc, e);

    // --- block 0 ---
    k_agg1<<<gN, B, 0, stream>>>(x, rp, esrc, agg0, n);
    k_mlp0<<<gN, B, 0, stream>>>(agg0, W1_0, b1_0, W2_0, b2_0, hP, n);

    // --- blocks 1..8 (residual) ---
    float* A = hP;
    float* Bf = hQ;
    for (int i = 0; i < 8; ++i) {
        k_agg32<<<gA, B, 0, stream>>>(A, rp, esrc, Bf, n);
        k_mlp_mid<<<gN, B, 0, stream>>>(Bf, A, W1m + i * 512, b1m + i * 16,
                                        W2m + i * 512, b2m + i * 32, Bf, n);
        float* t = A; A = Bf; Bf = t;
    }

    // --- block 9 ---
    k_agg32<<<gA, B, 0, stream>>>(A, rp, esrc, Bf, n);
    k_last<<<gN, B, 0, stream>>>(Bf, Wl, (float*)d_out, n);
}

// Round 2
// 894.632 us; speedup vs baseline: 2.6586x; 2.6586x over previous
//
#include <hip/hip_runtime.h>

// ---------------------------------------------------------------------------
// GIN, round 2: CSR pull-gather + bf16 state + fully fused per-block kernels.
// h [N,32] stored bf16 (64B/row) -> random gather traffic halved, fits caches
// better. All arithmetic in f32; only inter-round storage is bf16.
// Each GIN block = ONE kernel: 32 lanes/node gather -> LDS -> MLP -> residual
// -> coalesced bf16 row write. No separate MLP pass, no float atomics.
// ---------------------------------------------------------------------------

typedef unsigned short ushort_t;
typedef unsigned int uint_t;

static __device__ __forceinline__ float selu_f(float x) {
    const float scale = 1.0507009873554805f;
    const float alpha = 1.6732632423543772f;
    return x > 0.f ? scale * x : scale * alpha * (__expf(x) - 1.f);
}

static __device__ __forceinline__ float b2f(ushort_t u) {
    union { uint_t i; float f; } v;
    v.i = ((uint_t)u) << 16;
    return v.f;
}

static __device__ __forceinline__ ushort_t f2b(float f) {
    // round-to-nearest-even bf16 (values are finite; no NaN handling needed)
    uint_t x = __float_as_uint(f);
    uint_t r = (x + 0x7FFFu + ((x >> 16) & 1u)) >> 16;
    return (ushort_t)r;
}

// ---- CSR build -------------------------------------------------------------

__global__ void k_count(const int* __restrict__ dst, int* __restrict__ cnt, int e) {
    int i = blockIdx.x * blockDim.x + threadIdx.x;
    if (i < e) atomicAdd(&cnt[dst[i]], 1);
}

__global__ void k_scan1(const int* __restrict__ cnt, int* __restrict__ rp,
                        int* __restrict__ bsum, int n) {
    int tb = blockIdx.x * 1024 + threadIdx.x * 4;
    int c0 = (tb + 0 < n) ? cnt[tb + 0] : 0;
    int c1 = (tb + 1 < n) ? cnt[tb + 1] : 0;
    int c2 = (tb + 2 < n) ? cnt[tb + 2] : 0;
    int c3 = (tb + 3 < n) ? cnt[tb + 3] : 0;
    int t = c0 + c1 + c2 + c3;
    int lane = threadIdx.x & 63, wave = threadIdx.x >> 6;
    int inc = t;
    #pragma unroll
    for (int d = 1; d < 64; d <<= 1) {
        int v = __shfl_up(inc, d, 64);
        if (lane >= d) inc += v;
    }
    __shared__ int wtot[4];
    if (lane == 63) wtot[wave] = inc;
    __syncthreads();
    int woff = 0;
    #pragma unroll
    for (int w = 0; w < 4; ++w)
        if (w < wave) woff += wtot[w];
    int excl = woff + inc - t;
    if (tb + 0 < n) rp[tb + 0] = excl;
    if (tb + 1 < n) rp[tb + 1] = excl + c0;
    if (tb + 2 < n) rp[tb + 2] = excl + c0 + c1;
    if (tb + 3 < n) rp[tb + 3] = excl + c0 + c1 + c2;
    if (threadIdx.x == 255) bsum[blockIdx.x] = woff + inc;
}

__global__ void k_scan2(int* bsum, int nb) {
    __shared__ int s[256];
    int t = (threadIdx.x < nb) ? bsum[threadIdx.x] : 0;
    s[threadIdx.x] = t;
    __syncthreads();
    #pragma unroll
    for (int d = 1; d < 256; d <<= 1) {
        int v = (threadIdx.x >= (unsigned)d) ? s[threadIdx.x - d] : 0;
        __syncthreads();
        s[threadIdx.x] += v;
        __syncthreads();
    }
    if (threadIdx.x < nb) bsum[threadIdx.x] = s[threadIdx.x] - t;
}

__global__ void k_scan3(int* __restrict__ rp, int* __restrict__ cur,
                        const int* __restrict__ bsum, int n, int e) {
    int i = blockIdx.x * blockDim.x + threadIdx.x;
    if (i < n) {
        int v = rp[i] + bsum[i >> 10];
        rp[i] = v;
        cur[i] = v;
    }
    if (i == 0) rp[n] = e;
}

__global__ void k_fill(const int* __restrict__ src, const int* __restrict__ dst,
                       int* cur, int* __restrict__ esrc, int e) {
    int i = blockIdx.x * blockDim.x + threadIdx.x;
    if (i < e) {
        int d = dst[i];
        int p = atomicAdd(&cur[d], 1);
        esrc[p] = src[i];
    }
}

// ---- block 0: agg(x) + MLP[1,16,32] -> bf16 h, one thread per node ---------

__global__ void k_b0(const float* __restrict__ x, const int* __restrict__ rp,
                     const int* __restrict__ esrc,
                     const float* __restrict__ W1, const float* __restrict__ b1,
                     const float* __restrict__ W2, const float* __restrict__ b2,
                     ushort_t* __restrict__ hout, int n) {
    __shared__ float sW1[16], sb1[16], sW2[512], sb2[32];
    if (threadIdx.x < 16) { sW1[threadIdx.x] = W1[threadIdx.x]; sb1[threadIdx.x] = b1[threadIdx.x]; }
    for (int t = threadIdx.x; t < 512; t += 256) sW2[t] = W2[t];
    if (threadIdx.x < 32) sb2[threadIdx.x] = b2[threadIdx.x];
    __syncthreads();
    int i = blockIdx.x * blockDim.x + threadIdx.x;
    if (i >= n) return;
    float a = x[i];
    int b = rp[i], en = rp[i + 1];
    for (int j = b; j < en; ++j) a += x[esrc[j]];
    float u[16];
    #pragma unroll
    for (int k = 0; k < 16; ++k) u[k] = selu_f(fmaf(a, sW1[k], sb1[k]));
    ushort_t row[32];
    #pragma unroll
    for (int j = 0; j < 32; ++j) {
        float acc = sb2[j];
        #pragma unroll
        for (int k = 0; k < 16; ++k) acc = fmaf(u[k], sW2[k * 32 + j], acc);
        row[j] = f2b(acc);
    }
    uint4* op = (uint4*)(hout + (size_t)i * 32);
    #pragma unroll
    for (int q = 0; q < 4; ++q) {
        uint4 v;
        v.x = (uint_t)row[q * 8 + 0] | ((uint_t)row[q * 8 + 1] << 16);
        v.y = (uint_t)row[q * 8 + 2] | ((uint_t)row[q * 8 + 3] << 16);
        v.z = (uint_t)row[q * 8 + 4] | ((uint_t)row[q * 8 + 5] << 16);
        v.w = (uint_t)row[q * 8 + 6] | ((uint_t)row[q * 8 + 7] << 16);
        op[q] = v;
    }
}

// ---- mid blocks: fused agg + MLP[32,16,32] + residual -----------------------
// 32 lanes per node (lane = channel). 8 nodes in flight per 256-thr block,
// 4 node-batches per block (amortizes weight staging). Gather reads are
// coalesced 64B bf16 rows; esrc read once per 32 edges + __shfl broadcast.

__global__ __launch_bounds__(256) void k_mid(
    const ushort_t* __restrict__ hin, const int* __restrict__ rp,
    const int* __restrict__ esrc,
    const float* __restrict__ W1, const float* __restrict__ b1,
    const float* __restrict__ W2, const float* __restrict__ b2,
    ushort_t* __restrict__ hout, int n) {
    __shared__ float sW1[512], sW2[512], sb1[16], sb2[32];
    __shared__ float sh[8][33];   // +1 pad: conflict-free strided access
    __shared__ float su[8][17];
    for (int t = threadIdx.x; t < 512; t += 256) { sW1[t] = W1[t]; sW2[t] = W2[t]; }
    if (threadIdx.x < 16) sb1[threadIdx.x] = b1[threadIdx.x];
    if (threadIdx.x < 32) sb2[threadIdx.x] = b2[threadIdx.x];
    __syncthreads();
    const int g = threadIdx.x >> 5;   // group (node slot) 0..7
    const int c = threadIdx.x & 31;   // channel

    for (int it = 0; it < 4; ++it) {
        int node = blockIdx.x * 32 + it * 8 + g;
        bool valid = node < n;
        float self = 0.f, acc = 0.f;
        if (valid) {
            self = b2f(hin[(size_t)node * 32 + c]);
            acc = self;
            int b = rp[node];
            int deg = rp[node + 1] - b;
            for (int base = 0; base < deg; base += 32) {
                int idx = base + c;
                int e = (idx < deg) ? esrc[b + idx] : 0;   // coalesced 128B
                int m = deg - base; if (m > 32) m = 32;
                for (int j = 0; j < m; ++j) {
                    int s = __shfl(e, j, 32);              // broadcast edge src
                    acc += b2f(hin[(size_t)s * 32 + c]);   // coalesced 64B row
                }
            }
        }
        sh[g][c] = acc;
        __syncthreads();
        if (c < 16) {
            float u = sb1[c];
            #pragma unroll
            for (int cc = 0; cc < 32; ++cc)
                u = fmaf(sh[g][cc], sW1[cc * 16 + c], u);  // sh broadcast, sW1 conflict-free
            su[g][c] = selu_f(u);
        }
        __syncthreads();
        if (valid) {
            float o = sb2[c];
            #pragma unroll
            for (int k = 0; k < 16; ++k)
                o = fmaf(su[g][k], sW2[k * 32 + c], o);    // su broadcast, sW2 bank c
            hout[(size_t)node * 32 + c] = f2b(o + self);   // residual; coalesced 64B
        }
        __syncthreads();
    }
}

// ---- last block: fused agg + Linear(32 -> 1) --------------------------------

__global__ void k_last(const ushort_t* __restrict__ hin, const int* __restrict__ rp,
                       const int* __restrict__ esrc, const float* __restrict__ W,
                       float* __restrict__ out, int n) {
    int node = blockIdx.x * 8 + (threadIdx.x >> 5);
    int c = threadIdx.x & 31;
    if (node >= n) return;
    float acc = b2f(hin[(size_t)node * 32 + c]);
    int b = rp[node];
    int deg = rp[node + 1] - b;
    for (int base = 0; base < deg; base += 32) {
        int idx = base + c;
        int e = (idx < deg) ? esrc[b + idx] : 0;
        int m = deg - base; if (m > 32) m = 32;
        for (int j = 0; j < m; ++j) {
            int s = __shfl(e, j, 32);
            acc += b2f(hin[(size_t)s * 32 + c]);
        }
    }
    float p = acc * W[c];
    #pragma unroll
    for (int m2 = 16; m2 >= 1; m2 >>= 1) p += __shfl_xor(p, m2, 32);
    if (c == 0) out[node] = p;
}

// ---------------------------------------------------------------------------

extern "C" void kernel_launch(void* const* d_in, const int* in_sizes, int n_in,
                              void* d_out, int out_size, void* d_ws, size_t ws_size,
                              hipStream_t stream) {
    const float* x    = (const float*)d_in[0];
    const int*   ei   = (const int*)d_in[1];
    const float* W1_0 = (const float*)d_in[2];
    const float* b1_0 = (const float*)d_in[3];
    const float* W2_0 = (const float*)d_in[4];
    const float* b2_0 = (const float*)d_in[5];
    const float* W1m  = (const float*)d_in[6];
    const float* b1m  = (const float*)d_in[7];
    const float* W2m  = (const float*)d_in[8];
    const float* b2m  = (const float*)d_in[9];
    const float* Wl   = (const float*)d_in[10];

    const int n = in_sizes[0];      // 100000 nodes
    const int e = in_sizes[1] / 2;  // 1.6M edges
    const int* src  = ei;
    const int* dstp = ei + e;

    char* ws = (char*)d_ws;
    size_t off = 0;
    auto alloc = [&](size_t bytes) -> char* {
        char* p = ws + off;
        off += (bytes + 255) & ~size_t(255);
        return p;
    };
    ushort_t* hP  = (ushort_t*)alloc((size_t)n * 32 * 2);
    ushort_t* hQ  = (ushort_t*)alloc((size_t)n * 32 * 2);
    int* rp   = (int*)alloc((size_t)(n + 1) * 4);
    int* cur  = (int*)alloc((size_t)n * 4);
    int* cnt  = (int*)alloc((size_t)n * 4);
    int* esrc = (int*)alloc((size_t)e * 4);
    int* bsum = (int*)alloc(4096);
    (void)ws_size;

    const int B = 256;
    const int gE = (e + B - 1) / B;
    const int gN = (n + B - 1) / B;
    const int nb = (n + 1023) / 1024;
    const int gM = (n + 31) / 32;      // k_mid: 32 nodes/block
    const int gL = (n + 7) / 8;        // k_last: 8 nodes/block

    // --- CSR build (once per launch) ---
    hipMemsetAsync(cnt, 0, (size_t)n * 4, stream);
    k_count<<<gE, B, 0, stream>>>(dstp, cnt, e);
    k_scan1<<<nb, B, 0, stream>>>(cnt, rp, bsum, n);
    k_scan2<<<1, 256, 0, stream>>>(bsum, nb);
    k_scan3<<<gN, B, 0, stream>>>(rp, cur, bsum, n, e);
    k_fill<<<gE, B, 0, stream>>>(src, dstp, cur, esrc, e);

    // --- block 0 ---
    k_b0<<<gN, B, 0, stream>>>(x, rp, esrc, W1_0, b1_0, W2_0, b2_0, hP, n);

    // --- blocks 1..8 (fused agg + MLP + residual) ---
    ushort_t* A = hP;
    ushort_t* Bf = hQ;
    for (int i = 0; i < 8; ++i) {
        k_mid<<<gM, B, 0, stream>>>(A, rp, esrc, W1m + i * 512, b1m + i * 16,
                                    W2m + i * 512, b2m + i * 32, Bf, n);
        ushort_t* t = A; A = Bf; Bf = t;
    }

    // --- block 9 ---
    k_last<<<gL, B, 0, stream>>>(A, rp, esrc, Wl, (float*)d_out, n);
}

// Round 3
// 726.728 us; speedup vs baseline: 3.2729x; 1.2310x over previous
//
#include <hip/hip_runtime.h>

// ---------------------------------------------------------------------------
// GIN, round 3: CSR pull-gather + bf16 state, gather restructured to
// 4-lanes-per-node with uint4 (8 bf16) per lane: one wave load = 16 rows,
// MLP fully in registers (shfl_xor reduce), no LDS h-staging, no syncthreads
// in the hot path. CSR build unchanged from round 2.
// ---------------------------------------------------------------------------

typedef unsigned short ushort_t;
typedef unsigned int uint_t;

static __device__ __forceinline__ float selu_f(float x) {
    const float scale = 1.0507009873554805f;
    const float alpha = 1.6732632423543772f;
    return x > 0.f ? scale * x : scale * alpha * (__expf(x) - 1.f);
}

static __device__ __forceinline__ ushort_t f2b(float f) {
    uint_t x = __float_as_uint(f);
    uint_t r = (x + 0x7FFFu + ((x >> 16) & 1u)) >> 16;
    return (ushort_t)r;
}

static __device__ __forceinline__ void unpack8(uint4 v, float* f) {
    f[0] = __uint_as_float(v.x << 16);
    f[1] = __uint_as_float(v.x & 0xffff0000u);
    f[2] = __uint_as_float(v.y << 16);
    f[3] = __uint_as_float(v.y & 0xffff0000u);
    f[4] = __uint_as_float(v.z << 16);
    f[5] = __uint_as_float(v.z & 0xffff0000u);
    f[6] = __uint_as_float(v.w << 16);
    f[7] = __uint_as_float(v.w & 0xffff0000u);
}

static __device__ __forceinline__ void addrow8(uint4 v, float* acc) {
    acc[0] += __uint_as_float(v.x << 16);
    acc[1] += __uint_as_float(v.x & 0xffff0000u);
    acc[2] += __uint_as_float(v.y << 16);
    acc[3] += __uint_as_float(v.y & 0xffff0000u);
    acc[4] += __uint_as_float(v.z << 16);
    acc[5] += __uint_as_float(v.z & 0xffff0000u);
    acc[6] += __uint_as_float(v.w << 16);
    acc[7] += __uint_as_float(v.w & 0xffff0000u);
}

// ---- CSR build (unchanged) -------------------------------------------------

__global__ void k_count(const int* __restrict__ dst, int* __restrict__ cnt, int e) {
    int i = blockIdx.x * blockDim.x + threadIdx.x;
    if (i < e) atomicAdd(&cnt[dst[i]], 1);
}

__global__ void k_scan1(const int* __restrict__ cnt, int* __restrict__ rp,
                        int* __restrict__ bsum, int n) {
    int tb = blockIdx.x * 1024 + threadIdx.x * 4;
    int c0 = (tb + 0 < n) ? cnt[tb + 0] : 0;
    int c1 = (tb + 1 < n) ? cnt[tb + 1] : 0;
    int c2 = (tb + 2 < n) ? cnt[tb + 2] : 0;
    int c3 = (tb + 3 < n) ? cnt[tb + 3] : 0;
    int t = c0 + c1 + c2 + c3;
    int lane = threadIdx.x & 63, wave = threadIdx.x >> 6;
    int inc = t;
    #pragma unroll
    for (int d = 1; d < 64; d <<= 1) {
        int v = __shfl_up(inc, d, 64);
        if (lane >= d) inc += v;
    }
    __shared__ int wtot[4];
    if (lane == 63) wtot[wave] = inc;
    __syncthreads();
    int woff = 0;
    #pragma unroll
    for (int w = 0; w < 4; ++w)
        if (w < wave) woff += wtot[w];
    int excl = woff + inc - t;
    if (tb + 0 < n) rp[tb + 0] = excl;
    if (tb + 1 < n) rp[tb + 1] = excl + c0;
    if (tb + 2 < n) rp[tb + 2] = excl + c0 + c1;
    if (tb + 3 < n) rp[tb + 3] = excl + c0 + c1 + c2;
    if (threadIdx.x == 255) bsum[blockIdx.x] = woff + inc;
}

__global__ void k_scan2(int* bsum, int nb) {
    __shared__ int s[256];
    int t = (threadIdx.x < nb) ? bsum[threadIdx.x] : 0;
    s[threadIdx.x] = t;
    __syncthreads();
    #pragma unroll
    for (int d = 1; d < 256; d <<= 1) {
        int v = (threadIdx.x >= (unsigned)d) ? s[threadIdx.x - d] : 0;
        __syncthreads();
        s[threadIdx.x] += v;
        __syncthreads();
    }
    if (threadIdx.x < nb) bsum[threadIdx.x] = s[threadIdx.x] - t;
}

__global__ void k_scan3(int* __restrict__ rp, int* __restrict__ cur,
                        const int* __restrict__ bsum, int n, int e) {
    int i = blockIdx.x * blockDim.x + threadIdx.x;
    if (i < n) {
        int v = rp[i] + bsum[i >> 10];
        rp[i] = v;
        cur[i] = v;
    }
    if (i == 0) rp[n] = e;
}

__global__ void k_fill(const int* __restrict__ src, const int* __restrict__ dst,
                       int* cur, int* __restrict__ esrc, int e) {
    int i = blockIdx.x * blockDim.x + threadIdx.x;
    if (i < e) {
        int d = dst[i];
        int p = atomicAdd(&cur[d], 1);
        esrc[p] = src[i];
    }
}

// ---- block 0: agg(x) + MLP[1,16,32] -> bf16 h, one thread per node ---------

__global__ void k_b0(const float* __restrict__ x, const int* __restrict__ rp,
                     const int* __restrict__ esrc,
                     const float* __restrict__ W1, const float* __restrict__ b1,
                     const float* __restrict__ W2, const float* __restrict__ b2,
                     ushort_t* __restrict__ hout, int n) {
    __shared__ float sW1[16], sb1[16], sW2[512], sb2[32];
    if (threadIdx.x < 16) { sW1[threadIdx.x] = W1[threadIdx.x]; sb1[threadIdx.x] = b1[threadIdx.x]; }
    for (int t = threadIdx.x; t < 512; t += 256) sW2[t] = W2[t];
    if (threadIdx.x < 32) sb2[threadIdx.x] = b2[threadIdx.x];
    __syncthreads();
    int i = blockIdx.x * blockDim.x + threadIdx.x;
    if (i >= n) return;
    float a = x[i];
    int b = rp[i], en = rp[i + 1];
    for (int j = b; j < en; ++j) a += x[esrc[j]];
    float u[16];
    #pragma unroll
    for (int k = 0; k < 16; ++k) u[k] = selu_f(fmaf(a, sW1[k], sb1[k]));
    ushort_t row[32];
    #pragma unroll
    for (int j = 0; j < 32; ++j) {
        float acc = sb2[j];
        #pragma unroll
        for (int k = 0; k < 16; ++k) acc = fmaf(u[k], sW2[k * 32 + j], acc);
        row[j] = f2b(acc);
    }
    uint4* op = (uint4*)(hout + (size_t)i * 32);
    #pragma unroll
    for (int q = 0; q < 4; ++q) {
        uint4 v;
        v.x = (uint_t)row[q * 8 + 0] | ((uint_t)row[q * 8 + 1] << 16);
        v.y = (uint_t)row[q * 8 + 2] | ((uint_t)row[q * 8 + 3] << 16);
        v.z = (uint_t)row[q * 8 + 4] | ((uint_t)row[q * 8 + 5] << 16);
        v.w = (uint_t)row[q * 8 + 6] | ((uint_t)row[q * 8 + 7] << 16);
        op[q] = v;
    }
}

// ---- mid blocks: fused agg + MLP[32,16,32] + residual -----------------------
// 4 lanes per node; lane handles 8 channels (one uint4 = 16B of the 64B row).
// One wave-wide load = 16 rows. MLP in registers via shfl_xor(width=4).

__global__ __launch_bounds__(256) void k_mid(
    const ushort_t* __restrict__ hin, const int* __restrict__ rp,
    const int* __restrict__ esrc,
    const float* __restrict__ W1, const float* __restrict__ b1,
    const float* __restrict__ W2, const float* __restrict__ b2,
    ushort_t* __restrict__ hout, int n) {
    __shared__ float sW1T[512];  // [k][c] = W1[c][k]  (transposed for bank-free reads)
    __shared__ float sW2[512];   // [k][j] as stored
    __shared__ float sb1[16], sb2[32];
    for (int t = threadIdx.x; t < 512; t += 256) {
        int c = t >> 4, k = t & 15;
        sW1T[k * 32 + c] = W1[t];
        sW2[t] = W2[t];
    }
    if (threadIdx.x < 16) sb1[threadIdx.x] = b1[threadIdx.x];
    else if (threadIdx.x < 48) sb2[threadIdx.x - 16] = b2[threadIdx.x - 16];
    __syncthreads();

    const int lane4 = threadIdx.x & 3;
    const int node = blockIdx.x * 64 + (threadIdx.x >> 2);
    if (node >= n) return;
    const int c0 = lane4 * 8;

    const uint4* hrows = (const uint4*)hin;   // 4 uint4 per 32-ch row
    uint4 sv = hrows[(size_t)node * 4 + lane4];
    float self0[8], acc[8];
    unpack8(sv, self0);
    #pragma unroll
    for (int q = 0; q < 8; ++q) acc[q] = self0[q];

    int b = rp[node];
    int deg = rp[node + 1] - b;
    for (int j0 = 0; j0 < deg; j0 += 4) {
        int jj = j0 + lane4;
        int e4 = (jj < deg) ? esrc[b + jj] : 0;
        int m = deg - j0; if (m > 4) m = 4;
        #pragma unroll
        for (int t = 0; t < 4; ++t) {
            if (t >= m) break;
            int s = __shfl(e4, t, 4);
            uint4 v = hrows[(size_t)s * 4 + lane4];
            addrow8(v, acc);
        }
    }

    // hidden layer: partial over this lane's 8 channels, reduce across 4 lanes
    float pu[16];
    #pragma unroll
    for (int k = 0; k < 16; ++k) pu[k] = 0.f;
    #pragma unroll
    for (int q = 0; q < 8; ++q) {
        float vq = acc[q];
        #pragma unroll
        for (int k = 0; k < 16; ++k)
            pu[k] = fmaf(vq, sW1T[k * 32 + c0 + q], pu[k]);
    }
    #pragma unroll
    for (int k = 0; k < 16; ++k) {
        float p = pu[k];
        p += __shfl_xor(p, 1, 4);
        p += __shfl_xor(p, 2, 4);
        pu[k] = selu_f(p + sb1[k]);
    }

    // output layer + residual, pack bf16, one uint4 store per lane
    ushort_t r[8];
    #pragma unroll
    for (int q = 0; q < 8; ++q) {
        int j = c0 + q;
        float o = sb2[j];
        #pragma unroll
        for (int k = 0; k < 16; ++k) o = fmaf(pu[k], sW2[k * 32 + j], o);
        r[q] = f2b(o + self0[q]);
    }
    uint4 ov;
    ov.x = (uint_t)r[0] | ((uint_t)r[1] << 16);
    ov.y = (uint_t)r[2] | ((uint_t)r[3] << 16);
    ov.z = (uint_t)r[4] | ((uint_t)r[5] << 16);
    ov.w = (uint_t)r[6] | ((uint_t)r[7] << 16);
    ((uint4*)hout)[(size_t)node * 4 + lane4] = ov;
}

// ---- last block: fused agg + Linear(32 -> 1), same gather geometry ----------

__global__ __launch_bounds__(256) void k_last(
    const ushort_t* __restrict__ hin, const int* __restrict__ rp,
    const int* __restrict__ esrc, const float* __restrict__ W,
    float* __restrict__ out, int n) {
    const int lane4 = threadIdx.x & 3;
    const int node = blockIdx.x * 64 + (threadIdx.x >> 2);
    if (node >= n) return;
    const int c0 = lane4 * 8;

    const uint4* hrows = (const uint4*)hin;
    uint4 sv = hrows[(size_t)node * 4 + lane4];
    float acc[8];
    unpack8(sv, acc);

    int b = rp[node];
    int deg = rp[node + 1] - b;
    for (int j0 = 0; j0 < deg; j0 += 4) {
        int jj = j0 + lane4;
        int e4 = (jj < deg) ? esrc[b + jj] : 0;
        int m = deg - j0; if (m > 4) m = 4;
        #pragma unroll
        for (int t = 0; t < 4; ++t) {
            if (t >= m) break;
            int s = __shfl(e4, t, 4);
            uint4 v = hrows[(size_t)s * 4 + lane4];
            addrow8(v, acc);
        }
    }

    float p = 0.f;
    #pragma unroll
    for (int q = 0; q < 8; ++q) p = fmaf(acc[q], W[c0 + q], p);
    p += __shfl_xor(p, 1, 4);
    p += __shfl_xor(p, 2, 4);
    if (lane4 == 0) out[node] = p;
}

// ---------------------------------------------------------------------------

extern "C" void kernel_launch(void* const* d_in, const int* in_sizes, int n_in,
                              void* d_out, int out_size, void* d_ws, size_t ws_size,
                              hipStream_t stream) {
    const float* x    = (const float*)d_in[0];
    const int*   ei   = (const int*)d_in[1];
    const float* W1_0 = (const float*)d_in[2];
    const float* b1_0 = (const float*)d_in[3];
    const float* W2_0 = (const float*)d_in[4];
    const float* b2_0 = (const float*)d_in[5];
    const float* W1m  = (const float*)d_in[6];
    const float* b1m  = (const float*)d_in[7];
    const float* W2m  = (const float*)d_in[8];
    const float* b2m  = (const float*)d_in[9];
    const float* Wl   = (const float*)d_in[10];

    const int n = in_sizes[0];      // 100000 nodes
    const int e = in_sizes[1] / 2;  // 1.6M edges
    const int* src  = ei;
    const int* dstp = ei + e;

    char* ws = (char*)d_ws;
    size_t off = 0;
    auto alloc = [&](size_t bytes) -> char* {
        char* p = ws + off;
        off += (bytes + 255) & ~size_t(255);
        return p;
    };
    ushort_t* hP  = (ushort_t*)alloc((size_t)n * 32 * 2);
    ushort_t* hQ  = (ushort_t*)alloc((size_t)n * 32 * 2);
    int* rp   = (int*)alloc((size_t)(n + 1) * 4);
    int* cur  = (int*)alloc((size_t)n * 4);
    int* cnt  = (int*)alloc((size_t)n * 4);
    int* esrc = (int*)alloc((size_t)e * 4);
    int* bsum = (int*)alloc(4096);
    (void)ws_size;

    const int B = 256;
    const int gE = (e + B - 1) / B;
    const int gN = (n + B - 1) / B;
    const int nb = (n + 1023) / 1024;
    const int gM = (n + 63) / 64;      // 64 nodes per 256-thr block (4 lanes/node)

    // --- CSR build (once per launch) ---
    hipMemsetAsync(cnt, 0, (size_t)n * 4, stream);
    k_count<<<gE, B, 0, stream>>>(dstp, cnt, e);
    k_scan1<<<nb, B, 0, stream>>>(cnt, rp, bsum, n);
    k_scan2<<<1, 256, 0, stream>>>(bsum, nb);
    k_scan3<<<gN, B, 0, stream>>>(rp, cur, bsum, n, e);
    k_fill<<<gE, B, 0, stream>>>(src, dstp, cur, esrc, e);

    // --- block 0 ---
    k_b0<<<gN, B, 0, stream>>>(x, rp, esrc, W1_0, b1_0, W2_0, b2_0, hP, n);

    // --- blocks 1..8 (fused agg + MLP + residual) ---
    ushort_t* A = hP;
    ushort_t* Bf = hQ;
    for (int i = 0; i < 8; ++i) {
        k_mid<<<gM, B, 0, stream>>>(A, rp, esrc, W1m + i * 512, b1m + i * 16,
                                    W2m + i * 512, b2m + i * 32, Bf, n);
        ushort_t* t = A; A = Bf; Bf = t;
    }

    // --- block 9 ---
    k_last<<<gM, B, 0, stream>>>(A, rp, esrc, Wl, (float*)d_out, n);
}

// Round 4
// 527.643 us; speedup vs baseline: 4.5078x; 1.3773x over previous
//
#include <hip/hip_runtime.h>
#include <hip/hip_fp16.h>

// ---------------------------------------------------------------------------
// GIN, round 4: CSR pull-gather, h state in f16 (packed __half2 accumulate),
// gather loop restructured to 8 independent row-loads in flight per lane
// (DPP quad-broadcast of edge indices, no serial shfl->load->add chain).
// MLP in registers, quad reductions via DPP. CSR build unchanged.
// ---------------------------------------------------------------------------

typedef unsigned short ushort_t;
typedef unsigned int uint_t;

struct alignas(16) H2x4 { __half2 x, y, z, w; };  // 8 f16 channels

static __device__ __forceinline__ float selu_f(float x) {
    const float scale = 1.0507009873554805f;
    const float alpha = 1.6732632423543772f;
    return x > 0.f ? scale * x : scale * alpha * (__expf(x) - 1.f);
}

// broadcast lane T (0..3) of each quad to the whole quad — v_mov_b32 dpp
template<int T>
static __device__ __forceinline__ int bcast4(int v) {
    return __builtin_amdgcn_mov_dpp(v, T * 0x55, 0xf, 0xf, true);
}
// quad xor-1 / xor-2 permutes for cross-lane reduction (VALU, no LDS)
static __device__ __forceinline__ float qxor1(float x) {
    return __int_as_float(__builtin_amdgcn_mov_dpp(__float_as_int(x), 177, 0xf, 0xf, true));
}
static __device__ __forceinline__ float qxor2(float x) {
    return __int_as_float(__builtin_amdgcn_mov_dpp(__float_as_int(x), 78, 0xf, 0xf, true));
}

static __device__ __forceinline__ void acc_add(__half2& a0, __half2& a1,
                                               __half2& a2, __half2& a3, H2x4 v) {
    a0 = __hadd2(a0, v.x); a1 = __hadd2(a1, v.y);
    a2 = __hadd2(a2, v.z); a3 = __hadd2(a3, v.w);
}

// ---- CSR build (unchanged) -------------------------------------------------

__global__ void k_count(const int* __restrict__ dst, int* __restrict__ cnt, int e) {
    int i = blockIdx.x * blockDim.x + threadIdx.x;
    if (i < e) atomicAdd(&cnt[dst[i]], 1);
}

__global__ void k_scan1(const int* __restrict__ cnt, int* __restrict__ rp,
                        int* __restrict__ bsum, int n) {
    int tb = blockIdx.x * 1024 + threadIdx.x * 4;
    int c0 = (tb + 0 < n) ? cnt[tb + 0] : 0;
    int c1 = (tb + 1 < n) ? cnt[tb + 1] : 0;
    int c2 = (tb + 2 < n) ? cnt[tb + 2] : 0;
    int c3 = (tb + 3 < n) ? cnt[tb + 3] : 0;
    int t = c0 + c1 + c2 + c3;
    int lane = threadIdx.x & 63, wave = threadIdx.x >> 6;
    int inc = t;
    #pragma unroll
    for (int d = 1; d < 64; d <<= 1) {
        int v = __shfl_up(inc, d, 64);
        if (lane >= d) inc += v;
    }
    __shared__ int wtot[4];
    if (lane == 63) wtot[wave] = inc;
    __syncthreads();
    int woff = 0;
    #pragma unroll
    for (int w = 0; w < 4; ++w)
        if (w < wave) woff += wtot[w];
    int excl = woff + inc - t;
    if (tb + 0 < n) rp[tb + 0] = excl;
    if (tb + 1 < n) rp[tb + 1] = excl + c0;
    if (tb + 2 < n) rp[tb + 2] = excl + c0 + c1;
    if (tb + 3 < n) rp[tb + 3] = excl + c0 + c1 + c2;
    if (threadIdx.x == 255) bsum[blockIdx.x] = woff + inc;
}

__global__ void k_scan2(int* bsum, int nb) {
    __shared__ int s[256];
    int t = (threadIdx.x < nb) ? bsum[threadIdx.x] : 0;
    s[threadIdx.x] = t;
    __syncthreads();
    #pragma unroll
    for (int d = 1; d < 256; d <<= 1) {
        int v = (threadIdx.x >= (unsigned)d) ? s[threadIdx.x - d] : 0;
        __syncthreads();
        s[threadIdx.x] += v;
        __syncthreads();
    }
    if (threadIdx.x < nb) bsum[threadIdx.x] = s[threadIdx.x] - t;
}

__global__ void k_scan3(int* __restrict__ rp, int* __restrict__ cur,
                        const int* __restrict__ bsum, int n, int e) {
    int i = blockIdx.x * blockDim.x + threadIdx.x;
    if (i < n) {
        int v = rp[i] + bsum[i >> 10];
        rp[i] = v;
        cur[i] = v;
    }
    if (i == 0) rp[n] = e;
}

__global__ void k_fill(const int* __restrict__ src, const int* __restrict__ dst,
                       int* cur, int* __restrict__ esrc, int e) {
    int i = blockIdx.x * blockDim.x + threadIdx.x;
    if (i < e) {
        int d = dst[i];
        int p = atomicAdd(&cur[d], 1);
        esrc[p] = src[i];
    }
}

// ---- block 0: agg(x) + MLP[1,16,32] -> f16 h, one thread per node ----------

__global__ void k_b0(const float* __restrict__ x, const int* __restrict__ rp,
                     const int* __restrict__ esrc,
                     const float* __restrict__ W1, const float* __restrict__ b1,
                     const float* __restrict__ W2, const float* __restrict__ b2,
                     __half2* __restrict__ hout, int n) {
    __shared__ float sW1[16], sb1[16], sW2[512], sb2[32];
    if (threadIdx.x < 16) { sW1[threadIdx.x] = W1[threadIdx.x]; sb1[threadIdx.x] = b1[threadIdx.x]; }
    for (int t = threadIdx.x; t < 512; t += 256) sW2[t] = W2[t];
    if (threadIdx.x < 32) sb2[threadIdx.x] = b2[threadIdx.x];
    __syncthreads();
    int i = blockIdx.x * blockDim.x + threadIdx.x;
    if (i >= n) return;
    float a = x[i];
    int b = rp[i], en = rp[i + 1];
    for (int j = b; j < en; ++j) a += x[esrc[j]];
    float u[16];
    #pragma unroll
    for (int k = 0; k < 16; ++k) u[k] = selu_f(fmaf(a, sW1[k], sb1[k]));
    float row[32];
    #pragma unroll
    for (int j = 0; j < 32; ++j) {
        float acc = sb2[j];
        #pragma unroll
        for (int k = 0; k < 16; ++k) acc = fmaf(u[k], sW2[k * 32 + j], acc);
        row[j] = acc;
    }
    H2x4* op = (H2x4*)hout + (size_t)i * 4;
    #pragma unroll
    for (int q = 0; q < 4; ++q) {
        H2x4 v;
        v.x = __floats2half2_rn(row[q * 8 + 0], row[q * 8 + 1]);
        v.y = __floats2half2_rn(row[q * 8 + 2], row[q * 8 + 3]);
        v.z = __floats2half2_rn(row[q * 8 + 4], row[q * 8 + 5]);
        v.w = __floats2half2_rn(row[q * 8 + 6], row[q * 8 + 7]);
        op[q] = v;
    }
}

// ---- mid blocks: fused agg + MLP[32,16,32] + residual -----------------------
// 4 lanes per node, 8 f16 channels (one H2x4) per lane. Gather processes 8
// edges per chunk with all 8 row-loads issued independently before use.

__global__ __launch_bounds__(256, 4) void k_mid(
    const __half2* __restrict__ hin, const int* __restrict__ rp,
    const int* __restrict__ esrc,
    const float* __restrict__ W1, const float* __restrict__ b1,
    const float* __restrict__ W2, const float* __restrict__ b2,
    __half2* __restrict__ hout, int n) {
    __shared__ float sW1T[512];  // [k][c] = W1[c][k]
    __shared__ float sW2[512];   // [k][j]
    __shared__ float sb1[16], sb2[32];
    for (int t = threadIdx.x; t < 512; t += 256) {
        int c = t >> 4, k = t & 15;
        sW1T[k * 32 + c] = W1[t];
        sW2[t] = W2[t];
    }
    if (threadIdx.x < 16) sb1[threadIdx.x] = b1[threadIdx.x];
    else if (threadIdx.x < 48) sb2[threadIdx.x - 16] = b2[threadIdx.x - 16];
    __syncthreads();

    const int lane4 = threadIdx.x & 3;
    const int node = blockIdx.x * 64 + (threadIdx.x >> 2);
    if (node >= n) return;
    const int c0 = lane4 * 8;

    const H2x4* rows = (const H2x4*)hin;
    H2x4 sv = rows[(size_t)node * 4 + lane4];
    __half2 a0 = sv.x, a1 = sv.y, a2 = sv.z, a3 = sv.w;

    int b = rp[node];
    int deg = rp[node + 1] - b;
    int j0 = 0;
    for (; j0 + 8 <= deg; j0 += 8) {
        int ea = esrc[b + j0 + lane4];
        int eb = esrc[b + j0 + 4 + lane4];
        int s0 = bcast4<0>(ea), s1 = bcast4<1>(ea), s2 = bcast4<2>(ea), s3 = bcast4<3>(ea);
        int s4 = bcast4<0>(eb), s5 = bcast4<1>(eb), s6 = bcast4<2>(eb), s7 = bcast4<3>(eb);
        H2x4 v0 = rows[(size_t)s0 * 4 + lane4];
        H2x4 v1 = rows[(size_t)s1 * 4 + lane4];
        H2x4 v2 = rows[(size_t)s2 * 4 + lane4];
        H2x4 v3 = rows[(size_t)s3 * 4 + lane4];
        H2x4 v4 = rows[(size_t)s4 * 4 + lane4];
        H2x4 v5 = rows[(size_t)s5 * 4 + lane4];
        H2x4 v6 = rows[(size_t)s6 * 4 + lane4];
        H2x4 v7 = rows[(size_t)s7 * 4 + lane4];
        acc_add(a0, a1, a2, a3, v0);
        acc_add(a0, a1, a2, a3, v1);
        acc_add(a0, a1, a2, a3, v2);
        acc_add(a0, a1, a2, a3, v3);
        acc_add(a0, a1, a2, a3, v4);
        acc_add(a0, a1, a2, a3, v5);
        acc_add(a0, a1, a2, a3, v6);
        acc_add(a0, a1, a2, a3, v7);
    }
    if (j0 + 4 <= deg) {
        int ea = esrc[b + j0 + lane4];
        int s0 = bcast4<0>(ea), s1 = bcast4<1>(ea), s2 = bcast4<2>(ea), s3 = bcast4<3>(ea);
        H2x4 v0 = rows[(size_t)s0 * 4 + lane4];
        H2x4 v1 = rows[(size_t)s1 * 4 + lane4];
        H2x4 v2 = rows[(size_t)s2 * 4 + lane4];
        H2x4 v3 = rows[(size_t)s3 * 4 + lane4];
        acc_add(a0, a1, a2, a3, v0);
        acc_add(a0, a1, a2, a3, v1);
        acc_add(a0, a1, a2, a3, v2);
        acc_add(a0, a1, a2, a3, v3);
        j0 += 4;
    }
    for (; j0 < deg; ++j0) {
        int s = esrc[b + j0];
        H2x4 v = rows[(size_t)s * 4 + lane4];
        acc_add(a0, a1, a2, a3, v);
    }

    float2 f0 = __half22float2(a0), f1 = __half22float2(a1),
           f2 = __half22float2(a2), f3 = __half22float2(a3);
    float av[8] = {f0.x, f0.y, f1.x, f1.y, f2.x, f2.y, f3.x, f3.y};

    // hidden layer: partials over this lane's 8 channels, quad-reduce via DPP
    float pu[16];
    #pragma unroll
    for (int k = 0; k < 16; ++k) pu[k] = 0.f;
    #pragma unroll
    for (int q = 0; q < 8; ++q) {
        float vq = av[q];
        #pragma unroll
        for (int k = 0; k < 16; ++k)
            pu[k] = fmaf(vq, sW1T[k * 32 + c0 + q], pu[k]);
    }
    #pragma unroll
    for (int k = 0; k < 16; ++k) {
        float p = pu[k];
        p += qxor1(p);
        p += qxor2(p);
        pu[k] = selu_f(p + sb1[k]);
    }

    // output layer + residual -> f16 row
    float o[8];
    #pragma unroll
    for (int q = 0; q < 8; ++q) {
        float oo = sb2[c0 + q];
        #pragma unroll
        for (int k = 0; k < 16; ++k) oo = fmaf(pu[k], sW2[k * 32 + c0 + q], oo);
        o[q] = oo;
    }
    float2 sf0 = __half22float2(sv.x), sf1 = __half22float2(sv.y),
           sf2 = __half22float2(sv.z), sf3 = __half22float2(sv.w);
    H2x4 ov;
    ov.x = __floats2half2_rn(o[0] + sf0.x, o[1] + sf0.y);
    ov.y = __floats2half2_rn(o[2] + sf1.x, o[3] + sf1.y);
    ov.z = __floats2half2_rn(o[4] + sf2.x, o[5] + sf2.y);
    ov.w = __floats2half2_rn(o[6] + sf3.x, o[7] + sf3.y);
    ((H2x4*)hout)[(size_t)node * 4 + lane4] = ov;
}

// ---- last block: fused agg + Linear(32 -> 1) --------------------------------

__global__ __launch_bounds__(256, 4) void k_last(
    const __half2* __restrict__ hin, const int* __restrict__ rp,
    const int* __restrict__ esrc, const float* __restrict__ W,
    float* __restrict__ out, int n) {
    const int lane4 = threadIdx.x & 3;
    const int node = blockIdx.x * 64 + (threadIdx.x >> 2);
    if (node >= n) return;
    const int c0 = lane4 * 8;

    const H2x4* rows = (const H2x4*)hin;
    H2x4 sv = rows[(size_t)node * 4 + lane4];
    __half2 a0 = sv.x, a1 = sv.y, a2 = sv.z, a3 = sv.w;

    int b = rp[node];
    int deg = rp[node + 1] - b;
    int j0 = 0;
    for (; j0 + 8 <= deg; j0 += 8) {
        int ea = esrc[b + j0 + lane4];
        int eb = esrc[b + j0 + 4 + lane4];
        int s0 = bcast4<0>(ea), s1 = bcast4<1>(ea), s2 = bcast4<2>(ea), s3 = bcast4<3>(ea);
        int s4 = bcast4<0>(eb), s5 = bcast4<1>(eb), s6 = bcast4<2>(eb), s7 = bcast4<3>(eb);
        H2x4 v0 = rows[(size_t)s0 * 4 + lane4];
        H2x4 v1 = rows[(size_t)s1 * 4 + lane4];
        H2x4 v2 = rows[(size_t)s2 * 4 + lane4];
        H2x4 v3 = rows[(size_t)s3 * 4 + lane4];
        H2x4 v4 = rows[(size_t)s4 * 4 + lane4];
        H2x4 v5 = rows[(size_t)s5 * 4 + lane4];
        H2x4 v6 = rows[(size_t)s6 * 4 + lane4];
        H2x4 v7 = rows[(size_t)s7 * 4 + lane4];
        acc_add(a0, a1, a2, a3, v0);
        acc_add(a0, a1, a2, a3, v1);
        acc_add(a0, a1, a2, a3, v2);
        acc_add(a0, a1, a2, a3, v3);
        acc_add(a0, a1, a2, a3, v4);
        acc_add(a0, a1, a2, a3, v5);
        acc_add(a0, a1, a2, a3, v6);
        acc_add(a0, a1, a2, a3, v7);
    }
    if (j0 + 4 <= deg) {
        int ea = esrc[b + j0 + lane4];
        int s0 = bcast4<0>(ea), s1 = bcast4<1>(ea), s2 = bcast4<2>(ea), s3 = bcast4<3>(ea);
        H2x4 v0 = rows[(size_t)s0 * 4 + lane4];
        H2x4 v1 = rows[(size_t)s1 * 4 + lane4];
        H2x4 v2 = rows[(size_t)s2 * 4 + lane4];
        H2x4 v3 = rows[(size_t)s3 * 4 + lane4];
        acc_add(a0, a1, a2, a3, v0);
        acc_add(a0, a1, a2, a3, v1);
        acc_add(a0, a1, a2, a3, v2);
        acc_add(a0, a1, a2, a3, v3);
        j0 += 4;
    }
    for (; j0 < deg; ++j0) {
        int s = esrc[b + j0];
        H2x4 v = rows[(size_t)s * 4 + lane4];
        acc_add(a0, a1, a2, a3, v);
    }

    float2 f0 = __half22float2(a0), f1 = __half22float2(a1),
           f2 = __half22float2(a2), f3 = __half22float2(a3);
    float p = 0.f;
    p = fmaf(f0.x, W[c0 + 0], p);
    p = fmaf(f0.y, W[c0 + 1], p);
    p = fmaf(f1.x, W[c0 + 2], p);
    p = fmaf(f1.y, W[c0 + 3], p);
    p = fmaf(f2.x, W[c0 + 4], p);
    p = fmaf(f2.y, W[c0 + 5], p);
    p = fmaf(f3.x, W[c0 + 6], p);
    p = fmaf(f3.y, W[c0 + 7], p);
    p += qxor1(p);
    p += qxor2(p);
    if (lane4 == 0) out[node] = p;
}

// ---------------------------------------------------------------------------

extern "C" void kernel_launch(void* const* d_in, const int* in_sizes, int n_in,
                              void* d_out, int out_size, void* d_ws, size_t ws_size,
                              hipStream_t stream) {
    const float* x    = (const float*)d_in[0];
    const int*   ei   = (const int*)d_in[1];
    const float* W1_0 = (const float*)d_in[2];
    const float* b1_0 = (const float*)d_in[3];
    const float* W2_0 = (const float*)d_in[4];
    const float* b2_0 = (const float*)d_in[5];
    const float* W1m  = (const float*)d_in[6];
    const float* b1m  = (const float*)d_in[7];
    const float* W2m  = (const float*)d_in[8];
    const float* b2m  = (const float*)d_in[9];
    const float* Wl   = (const float*)d_in[10];

    const int n = in_sizes[0];      // 100000 nodes
    const int e = in_sizes[1] / 2;  // 1.6M edges
    const int* src  = ei;
    const int* dstp = ei + e;

    char* ws = (char*)d_ws;
    size_t off = 0;
    auto alloc = [&](size_t bytes) -> char* {
        char* p = ws + off;
        off += (bytes + 255) & ~size_t(255);
        return p;
    };
    __half2* hP = (__half2*)alloc((size_t)n * 32 * 2);
    __half2* hQ = (__half2*)alloc((size_t)n * 32 * 2);
    int* rp   = (int*)alloc((size_t)(n + 1) * 4);
    int* cur  = (int*)alloc((size_t)n * 4);
    int* cnt  = (int*)alloc((size_t)n * 4);
    int* esrc = (int*)alloc((size_t)e * 4);
    int* bsum = (int*)alloc(4096);
    (void)ws_size;

    const int B = 256;
    const int gE = (e + B - 1) / B;
    const int gN = (n + B - 1) / B;
    const int nb = (n + 1023) / 1024;
    const int gM = (n + 63) / 64;      // 64 nodes per 256-thr block (4 lanes/node)

    // --- CSR build (once per launch) ---
    hipMemsetAsync(cnt, 0, (size_t)n * 4, stream);
    k_count<<<gE, B, 0, stream>>>(dstp, cnt, e);
    k_scan1<<<nb, B, 0, stream>>>(cnt, rp, bsum, n);
    k_scan2<<<1, 256, 0, stream>>>(bsum, nb);
    k_scan3<<<gN, B, 0, stream>>>(rp, cur, bsum, n, e);
    k_fill<<<gE, B, 0, stream>>>(src, dstp, cur, esrc, e);

    // --- block 0 ---
    k_b0<<<gN, B, 0, stream>>>(x, rp, esrc, W1_0, b1_0, W2_0, b2_0, hP, n);

    // --- blocks 1..8 (fused agg + MLP + residual) ---
    __half2* A = hP;
    __half2* Bf = hQ;
    for (int i = 0; i < 8; ++i) {
        k_mid<<<gM, B, 0, stream>>>(A, rp, esrc, W1m + i * 512, b1m + i * 16,
                                    W2m + i * 512, b2m + i * 32, Bf, n);
        __half2* t = A; A = Bf; Bf = t;
    }

    // --- block 9 ---
    k_last<<<gM, B, 0, stream>>>(A, rp, esrc, Wl, (float*)d_out, n);
}

// Round 5
// 296.677 us; speedup vs baseline: 8.0171x; 1.7785x over previous
//
#include <hip/hip_runtime.h>
#include <hip/hip_fp16.h>

// ---------------------------------------------------------------------------
// GIN, round 5:
//  (a) CSR build rewritten as two-level counting sort (no global random
//      atomics, no 4B-scatter write amplification): bucket = dst>>8,
//      LDS histograms + per-bucket block-offset scan + LDS-cursor scatter of
//      packed pairs + per-bucket build of rp/esrc in an L2-hot region.
//  (b) project-before-aggregate: g = h@W1 (N x 16, f16) computed per-node,
//      gather sums g rows (32B instead of 64B), b1 added post-aggregation
//      (sum of biases would be wrong), then selu -> W2 -> +h residual.
//      Last block gathers scalar z = h@W_last.
// ---------------------------------------------------------------------------

typedef unsigned int uint_t;

#define NBLK 256          // blocks for hist/scatter passes (fixed chunking)
#define NBMAX 400         // >= number of buckets ((n+255)>>8)

struct alignas(16) H2x4 { __half2 x, y, z, w; };  // 8 f16 channels

static __device__ __forceinline__ float selu_f(float x) {
    const float scale = 1.0507009873554805f;
    const float alpha = 1.6732632423543772f;
    return x > 0.f ? scale * x : scale * alpha * (__expf(x) - 1.f);
}

// quad_perm DPP helpers (all within 4-lane quads; pairs stay inside quads)
static __device__ __forceinline__ int pb0(int v) {   // lanes {0,1}<-0, {2,3}<-2
    return __builtin_amdgcn_mov_dpp(v, 0xA0, 0xf, 0xf, true);
}
static __device__ __forceinline__ int pb1(int v) {   // lanes {0,1}<-1, {2,3}<-3
    return __builtin_amdgcn_mov_dpp(v, 0xF5, 0xf, 0xf, true);
}
static __device__ __forceinline__ float pswap(float x) {  // pair swap [1,0,3,2]
    return __int_as_float(__builtin_amdgcn_mov_dpp(__float_as_int(x), 0xB1, 0xf, 0xf, true));
}

static __device__ __forceinline__ void acc_add(__half2& a0, __half2& a1,
                                               __half2& a2, __half2& a3, H2x4 v) {
    a0 = __hadd2(a0, v.x); a1 = __hadd2(a1, v.y);
    a2 = __hadd2(a2, v.z); a3 = __hadd2(a3, v.w);
}

// ============================ CSR build v2 ==================================

// Pass A: per-block bucket histogram -> MT[bucket][block]
__global__ void k_hist(const int* __restrict__ dst, int* __restrict__ MT,
                       int e, int nb) {
    __shared__ int hist[NBMAX];
    for (int t = threadIdx.x; t < nb; t += 256) hist[t] = 0;
    __syncthreads();
    int chunk = (e + NBLK - 1) / NBLK;
    int lo = blockIdx.x * chunk, hi = min(e, lo + chunk);
    for (int i = lo + threadIdx.x; i < hi; i += 256)
        atomicAdd(&hist[dst[i] >> 8], 1);
    __syncthreads();
    for (int t = threadIdx.x; t < nb; t += 256)
        MT[t * NBLK + blockIdx.x] = hist[t];
}

// Pass S1: per-bucket exclusive scan across blocks; emit bucket totals
__global__ void k_cscan(int* __restrict__ MT, int* __restrict__ tot, int nb) {
    int k = blockIdx.x;
    int lane = threadIdx.x;  // 64
    int carry = 0;
    #pragma unroll
    for (int r = 0; r < NBLK; r += 64) {
        int v = MT[k * NBLK + r + lane];
        int inc = v;
        #pragma unroll
        for (int d = 1; d < 64; d <<= 1) {
            int w = __shfl_up(inc, d, 64);
            if (lane >= d) inc += w;
        }
        MT[k * NBLK + r + lane] = carry + inc - v;   // exclusive
        carry += __shfl(inc, 63, 64);
    }
    if (lane == 0) tot[k] = carry;
}

// Pass S2: exclusive scan of bucket totals -> base[nb+1]; also rp[n]=e
__global__ void k_bscan(const int* __restrict__ tot, int* __restrict__ base,
                        int* __restrict__ rp, int nb, int e, int n) {
    __shared__ int s[512];
    int t = threadIdx.x;
    int v = (t < nb) ? tot[t] : 0;
    s[t] = v;
    __syncthreads();
    #pragma unroll
    for (int d = 1; d < 512; d <<= 1) {
        int w = (t >= d) ? s[t - d] : 0;
        __syncthreads();
        s[t] += w;
        __syncthreads();
    }
    if (t < nb) base[t] = s[t] - v;
    if (t == nb - 1) base[nb] = s[t];
    if (t == 0) rp[n] = e;
}

// Pass C: scatter packed pairs (src | dlow<<24) into bucket-ordered array
__global__ void k_scatter(const int* __restrict__ src, const int* __restrict__ dst,
                          const int* __restrict__ MT, const int* __restrict__ base,
                          uint_t* __restrict__ pairs, int e, int nb) {
    __shared__ int cur[NBMAX];
    for (int t = threadIdx.x; t < nb; t += 256)
        cur[t] = base[t] + MT[t * NBLK + blockIdx.x];
    __syncthreads();
    int chunk = (e + NBLK - 1) / NBLK;
    int lo = blockIdx.x * chunk, hi = min(e, lo + chunk);
    for (int i = lo + threadIdx.x; i < hi; i += 256) {
        int d = dst[i];
        int pos = atomicAdd(&cur[d >> 8], 1);
        pairs[pos] = (uint_t)src[i] | ((uint_t)(d & 255) << 24);
    }
}

// Pass D: one block per bucket -> rp for its 256 nodes + esrc
__global__ void k_build(const uint_t* __restrict__ pairs, const int* __restrict__ base,
                        int* __restrict__ rp, int* __restrict__ esrc, int n) {
    int k = blockIdx.x;
    int bb = base[k], be = base[k + 1];
    __shared__ int cnt[256], cur[256], stmp[256];
    int t = threadIdx.x;
    cnt[t] = 0;
    __syncthreads();
    for (int i = bb + t; i < be; i += 256)
        atomicAdd(&cnt[pairs[i] >> 24], 1);
    __syncthreads();
    int v = cnt[t];
    stmp[t] = v;
    __syncthreads();
    #pragma unroll
    for (int d = 1; d < 256; d <<= 1) {
        int w = (t >= d) ? stmp[t - d] : 0;
        __syncthreads();
        stmp[t] += w;
        __syncthreads();
    }
    int excl = stmp[t] - v;
    int nd = k * 256 + t;
    if (nd < n) rp[nd] = bb + excl;
    cur[t] = bb + excl;
    __syncthreads();
    for (int i = bb + t; i < be; i += 256) {
        uint_t p = pairs[i];
        int pos = atomicAdd(&cur[p >> 24], 1);
        esrc[pos] = (int)(p & 0xFFFFFFu);
    }
}

// ============================ network kernels ===============================

// block 0: agg(x) + MLP[1,16,32] -> f16 h, one thread per node
__global__ void k_b0(const float* __restrict__ x, const int* __restrict__ rp,
                     const int* __restrict__ esrc,
                     const float* __restrict__ W1, const float* __restrict__ b1,
                     const float* __restrict__ W2, const float* __restrict__ b2,
                     __half2* __restrict__ hout, int n) {
    __shared__ float sW1[16], sb1[16], sW2[512], sb2[32];
    if (threadIdx.x < 16) { sW1[threadIdx.x] = W1[threadIdx.x]; sb1[threadIdx.x] = b1[threadIdx.x]; }
    for (int t = threadIdx.x; t < 512; t += 256) sW2[t] = W2[t];
    if (threadIdx.x < 32) sb2[threadIdx.x] = b2[threadIdx.x];
    __syncthreads();
    int i = blockIdx.x * blockDim.x + threadIdx.x;
    if (i >= n) return;
    float a = x[i];
    int b = rp[i], en = rp[i + 1];
    int j = b;
    for (; j + 4 <= en; j += 4) {
        int s0 = esrc[j], s1 = esrc[j + 1], s2 = esrc[j + 2], s3 = esrc[j + 3];
        float x0 = x[s0], x1 = x[s1], x2 = x[s2], x3 = x[s3];
        a += (x0 + x1) + (x2 + x3);
    }
    for (; j < en; ++j) a += x[esrc[j]];
    float u[16];
    #pragma unroll
    for (int k = 0; k < 16; ++k) u[k] = selu_f(fmaf(a, sW1[k], sb1[k]));
    float row[32];
    #pragma unroll
    for (int jj = 0; jj < 32; ++jj) {
        float acc = sb2[jj];
        #pragma unroll
        for (int k = 0; k < 16; ++k) acc = fmaf(u[k], sW2[k * 32 + jj], acc);
        row[jj] = acc;
    }
    H2x4* op = (H2x4*)hout + (size_t)i * 4;
    #pragma unroll
    for (int q = 0; q < 4; ++q) {
        H2x4 vv;
        vv.x = __floats2half2_rn(row[q * 8 + 0], row[q * 8 + 1]);
        vv.y = __floats2half2_rn(row[q * 8 + 2], row[q * 8 + 3]);
        vv.z = __floats2half2_rn(row[q * 8 + 4], row[q * 8 + 5]);
        vv.w = __floats2half2_rn(row[q * 8 + 6], row[q * 8 + 7]);
        op[q] = vv;
    }
}

// projection: g = h @ W1 (NO bias; bias added post-aggregation). One thr/node.
__global__ __launch_bounds__(256) void k_proj(const __half2* __restrict__ hin,
                                              const float* __restrict__ W1,
                                              __half2* __restrict__ g, int n) {
    __shared__ float sW[512];   // W1 [32][16] row-major
    for (int t = threadIdx.x; t < 512; t += 256) sW[t] = W1[t];
    __syncthreads();
    int i = blockIdx.x * 256 + threadIdx.x;
    if (i >= n) return;
    const H2x4* hr = (const H2x4*)hin + (size_t)i * 4;
    float hv[32];
    #pragma unroll
    for (int q = 0; q < 4; ++q) {
        H2x4 r = hr[q];
        float2 f0 = __half22float2(r.x), f1 = __half22float2(r.y),
               f2 = __half22float2(r.z), f3 = __half22float2(r.w);
        hv[q * 8 + 0] = f0.x; hv[q * 8 + 1] = f0.y;
        hv[q * 8 + 2] = f1.x; hv[q * 8 + 3] = f1.y;
        hv[q * 8 + 4] = f2.x; hv[q * 8 + 5] = f2.y;
        hv[q * 8 + 6] = f3.x; hv[q * 8 + 7] = f3.y;
    }
    float u[16];
    #pragma unroll
    for (int k = 0; k < 16; ++k) u[k] = 0.f;
    #pragma unroll
    for (int c = 0; c < 32; ++c) {
        float vc = hv[c];
        #pragma unroll
        for (int k = 0; k < 16; ++k) u[k] = fmaf(vc, sW[c * 16 + k], u[k]);
    }
    H2x4* op = (H2x4*)g + (size_t)i * 2;
    #pragma unroll
    for (int q = 0; q < 2; ++q) {
        H2x4 vv;
        vv.x = __floats2half2_rn(u[q * 8 + 0], u[q * 8 + 1]);
        vv.y = __floats2half2_rn(u[q * 8 + 2], u[q * 8 + 3]);
        vv.z = __floats2half2_rn(u[q * 8 + 4], u[q * 8 + 5]);
        vv.w = __floats2half2_rn(u[q * 8 + 6], u[q * 8 + 7]);
        op[q] = vv;
    }
}

// mid gather: u = sum g rows (2 lanes/node, 16B/lane), + b1, selu, @W2, +h.
__global__ __launch_bounds__(256, 4) void k_gmid(
    const __half2* __restrict__ gin, const __half2* __restrict__ hin,
    const int* __restrict__ rp, const int* __restrict__ esrc,
    const float* __restrict__ W2, const float* __restrict__ b1,
    const float* __restrict__ b2, __half2* __restrict__ hout, int n) {
    __shared__ float sW2[512], sb1[16], sb2[32];
    for (int t = threadIdx.x; t < 512; t += 256) sW2[t] = W2[t];
    if (threadIdx.x < 16) sb1[threadIdx.x] = b1[threadIdx.x];
    else if (threadIdx.x < 48) sb2[threadIdx.x - 16] = b2[threadIdx.x - 16];
    __syncthreads();

    const int lane2 = threadIdx.x & 1;
    const int node = blockIdx.x * 128 + (threadIdx.x >> 1);
    if (node >= n) return;

    const H2x4* grows = (const H2x4*)gin;
    H2x4 a = grows[(size_t)node * 2 + lane2];
    __half2 a0 = a.x, a1 = a.y, a2 = a.z, a3 = a.w;

    int b = rp[node];
    int deg = rp[node + 1] - b;
    int j0 = 0;
    for (; j0 + 8 <= deg; j0 += 8) {
        int e0 = esrc[b + j0 + lane2];
        int e1 = esrc[b + j0 + 2 + lane2];
        int e2 = esrc[b + j0 + 4 + lane2];
        int e3 = esrc[b + j0 + 6 + lane2];
        int s0 = pb0(e0), s1 = pb1(e0), s2 = pb0(e1), s3 = pb1(e1);
        int s4 = pb0(e2), s5 = pb1(e2), s6 = pb0(e3), s7 = pb1(e3);
        H2x4 v0 = grows[(size_t)s0 * 2 + lane2];
        H2x4 v1 = grows[(size_t)s1 * 2 + lane2];
        H2x4 v2 = grows[(size_t)s2 * 2 + lane2];
        H2x4 v3 = grows[(size_t)s3 * 2 + lane2];
        H2x4 v4 = grows[(size_t)s4 * 2 + lane2];
        H2x4 v5 = grows[(size_t)s5 * 2 + lane2];
        H2x4 v6 = grows[(size_t)s6 * 2 + lane2];
        H2x4 v7 = grows[(size_t)s7 * 2 + lane2];
        acc_add(a0, a1, a2, a3, v0);
        acc_add(a0, a1, a2, a3, v1);
        acc_add(a0, a1, a2, a3, v2);
        acc_add(a0, a1, a2, a3, v3);
        acc_add(a0, a1, a2, a3, v4);
        acc_add(a0, a1, a2, a3, v5);
        acc_add(a0, a1, a2, a3, v6);
        acc_add(a0, a1, a2, a3, v7);
    }
    for (; j0 < deg; ++j0) {
        int s = esrc[b + j0];
        H2x4 v = grows[(size_t)s * 2 + lane2];
        acc_add(a0, a1, a2, a3, v);
    }

    // u = selu(acc + b1) for this lane's 8 hidden channels
    float2 f0 = __half22float2(a0), f1 = __half22float2(a1),
           f2 = __half22float2(a2), f3 = __half22float2(a3);
    float u[8] = {f0.x, f0.y, f1.x, f1.y, f2.x, f2.y, f3.x, f3.y};
    const int kb = lane2 * 8;
    #pragma unroll
    for (int q = 0; q < 8; ++q) u[q] = selu_f(u[q] + sb1[kb + q]);

    // exchange with pair partner -> all 16 hidden values
    float ua[16];
    #pragma unroll
    for (int q = 0; q < 8; ++q) {
        float uo = pswap(u[q]);
        ua[q]     = lane2 ? uo   : u[q];
        ua[8 + q] = lane2 ? u[q] : uo;
    }

    // residual h row (this lane's 16 output channels = 32B)
    const H2x4* hrows = (const H2x4*)hin;
    H2x4 h0 = hrows[(size_t)node * 4 + lane2 * 2];
    H2x4 h1 = hrows[(size_t)node * 4 + lane2 * 2 + 1];
    float hv[16];
    {
        float2 g0 = __half22float2(h0.x), g1 = __half22float2(h0.y),
               g2 = __half22float2(h0.z), g3 = __half22float2(h0.w);
        float2 g4 = __half22float2(h1.x), g5 = __half22float2(h1.y),
               g6 = __half22float2(h1.z), g7 = __half22float2(h1.w);
        hv[0] = g0.x; hv[1] = g0.y; hv[2] = g1.x; hv[3] = g1.y;
        hv[4] = g2.x; hv[5] = g2.y; hv[6] = g3.x; hv[7] = g3.y;
        hv[8] = g4.x; hv[9] = g4.y; hv[10] = g5.x; hv[11] = g5.y;
        hv[12] = g6.x; hv[13] = g6.y; hv[14] = g7.x; hv[15] = g7.y;
    }

    const int jb = lane2 * 16;
    float o[16];
    #pragma unroll
    for (int q = 0; q < 16; ++q) {
        float oo = sb2[jb + q];
        #pragma unroll
        for (int k = 0; k < 16; ++k) oo = fmaf(ua[k], sW2[k * 32 + jb + q], oo);
        o[q] = oo + hv[q];
    }
    H2x4 o0, o1;
    o0.x = __floats2half2_rn(o[0], o[1]);   o0.y = __floats2half2_rn(o[2], o[3]);
    o0.z = __floats2half2_rn(o[4], o[5]);   o0.w = __floats2half2_rn(o[6], o[7]);
    o1.x = __floats2half2_rn(o[8], o[9]);   o1.y = __floats2half2_rn(o[10], o[11]);
    o1.z = __floats2half2_rn(o[12], o[13]); o1.w = __floats2half2_rn(o[14], o[15]);
    ((H2x4*)hout)[(size_t)node * 4 + lane2 * 2]     = o0;
    ((H2x4*)hout)[(size_t)node * 4 + lane2 * 2 + 1] = o1;
}

// last-block projection: z = h @ W_last (scalar per node)
__global__ __launch_bounds__(256) void k_projz(const __half2* __restrict__ hin,
                                               const float* __restrict__ W,
                                               float* __restrict__ z, int n) {
    __shared__ float sW[32];
    if (threadIdx.x < 32) sW[threadIdx.x] = W[threadIdx.x];
    __syncthreads();
    int i = blockIdx.x * 256 + threadIdx.x;
    if (i >= n) return;
    const H2x4* hr = (const H2x4*)hin + (size_t)i * 4;
    float acc = 0.f;
    #pragma unroll
    for (int q = 0; q < 4; ++q) {
        H2x4 r = hr[q];
        float2 f0 = __half22float2(r.x), f1 = __half22float2(r.y),
               f2 = __half22float2(r.z), f3 = __half22float2(r.w);
        acc = fmaf(f0.x, sW[q * 8 + 0], acc);
        acc = fmaf(f0.y, sW[q * 8 + 1], acc);
        acc = fmaf(f1.x, sW[q * 8 + 2], acc);
        acc = fmaf(f1.y, sW[q * 8 + 3], acc);
        acc = fmaf(f2.x, sW[q * 8 + 4], acc);
        acc = fmaf(f2.y, sW[q * 8 + 5], acc);
        acc = fmaf(f3.x, sW[q * 8 + 6], acc);
        acc = fmaf(f3.y, sW[q * 8 + 7], acc);
    }
    z[i] = acc;
}

// last-block gather: out = z + sum z[src], one thread per node
__global__ void k_gz(const float* __restrict__ z, const int* __restrict__ rp,
                     const int* __restrict__ esrc, float* __restrict__ out, int n) {
    int i = blockIdx.x * blockDim.x + threadIdx.x;
    if (i >= n) return;
    float acc = z[i];
    int b = rp[i], en = rp[i + 1];
    int j = b;
    for (; j + 4 <= en; j += 4) {
        int s0 = esrc[j], s1 = esrc[j + 1], s2 = esrc[j + 2], s3 = esrc[j + 3];
        float z0 = z[s0], z1 = z[s1], z2 = z[s2], z3 = z[s3];
        acc += (z0 + z1) + (z2 + z3);
    }
    for (; j < en; ++j) acc += z[esrc[j]];
    out[i] = acc;
}

// ---------------------------------------------------------------------------

extern "C" void kernel_launch(void* const* d_in, const int* in_sizes, int n_in,
                              void* d_out, int out_size, void* d_ws, size_t ws_size,
                              hipStream_t stream) {
    const float* x    = (const float*)d_in[0];
    const int*   ei   = (const int*)d_in[1];
    const float* W1_0 = (const float*)d_in[2];
    const float* b1_0 = (const float*)d_in[3];
    const float* W2_0 = (const float*)d_in[4];
    const float* b2_0 = (const float*)d_in[5];
    const float* W1m  = (const float*)d_in[6];
    const float* b1m  = (const float*)d_in[7];
    const float* W2m  = (const float*)d_in[8];
    const float* b2m  = (const float*)d_in[9];
    const float* Wl   = (const float*)d_in[10];

    const int n = in_sizes[0];      // 100000 nodes
    const int e = in_sizes[1] / 2;  // 1.6M edges
    const int* src  = ei;
    const int* dstp = ei + e;
    const int nb = (n + 255) >> 8;  // buckets (391)

    char* ws = (char*)d_ws;
    size_t off = 0;
    auto alloc = [&](size_t bytes) -> char* {
        char* p = ws + off;
        off += (bytes + 255) & ~size_t(255);
        return p;
    };
    __half2* hP   = (__half2*)alloc((size_t)n * 32 * 2);
    __half2* hQ   = (__half2*)alloc((size_t)n * 32 * 2);
    __half2* g    = (__half2*)alloc((size_t)n * 16 * 2);
    float*   z    = (float*)alloc((size_t)n * 4);
    int*     rp   = (int*)alloc((size_t)(n + 1) * 4);
    int*     esrc = (int*)alloc((size_t)e * 4);
    uint_t*  pairs= (uint_t*)alloc((size_t)e * 4);
    int*     MT   = (int*)alloc((size_t)NBMAX * NBLK * 4);
    int*     base = (int*)alloc((size_t)(NBMAX + 1) * 4);
    int*     tot  = (int*)alloc((size_t)NBMAX * 4);
    (void)ws_size;

    const int B = 256;
    const int gN = (n + B - 1) / B;
    const int gG = (n + 127) / 128;   // k_gmid: 128 nodes/block

    // --- CSR build (counting sort, once per launch) ---
    k_hist<<<NBLK, B, 0, stream>>>(dstp, MT, e, nb);
    k_cscan<<<nb, 64, 0, stream>>>(MT, tot, nb);
    k_bscan<<<1, 512, 0, stream>>>(tot, base, rp, nb, e, n);
    k_scatter<<<NBLK, B, 0, stream>>>(src, dstp, MT, base, pairs, e, nb);
    k_build<<<nb, B, 0, stream>>>(pairs, base, rp, esrc, n);

    // --- block 0 ---
    k_b0<<<gN, B, 0, stream>>>(x, rp, esrc, W1_0, b1_0, W2_0, b2_0, hP, n);

    // --- blocks 1..8: proj (h->g) then fused gather+MLP+residual ---
    __half2* A = hP;
    __half2* Bf = hQ;
    for (int i = 0; i < 8; ++i) {
        k_proj<<<gN, B, 0, stream>>>(A, W1m + i * 512, g, n);
        k_gmid<<<gG, B, 0, stream>>>(g, A, rp, esrc, W2m + i * 512,
                                     b1m + i * 16, b2m + i * 32, Bf, n);
        __half2* t = A; A = Bf; Bf = t;
    }

    // --- block 9: scalar projection then scalar gather ---
    k_projz<<<gN, B, 0, stream>>>(A, Wl, z, n);
    k_gz<<<gN, B, 0, stream>>>(z, rp, esrc, (float*)d_out, n);
}

// Round 7
// 267.728 us; speedup vs baseline: 8.8840x; 1.1081x over previous
//
#include <hip/hip_runtime.h>
#include <hip/hip_fp16.h>

// ---------------------------------------------------------------------------
// GIN, round 7 (= round 6 with typo fixed): counting-sort CSR, project-
// before-aggregate, f16 state, projection FUSED into epilogues:
//   k_b0g   : agg(x) + MLP0 -> h1  AND  g1 = h1 @ W1[0]
//   k_gmid<0>: gather(g_i) + b1,selu,W2,+res -> h_{i+1} AND g_{i+1} (in-reg)
//   k_gmid<1>: same but last round: z = h9 @ W_last instead of g
//   k_gz    : out = z + sum z[src]
// Deletes 8 k_proj + k_projz dispatches and their h-row round trips.
// ---------------------------------------------------------------------------

typedef unsigned int uint_t;

#define NBLK 256
#define NBMAX 400

struct alignas(16) H2x4 { __half2 x, y, z, w; };  // 8 f16 channels

static __device__ __forceinline__ float selu_f(float x) {
    const float scale = 1.0507009873554805f;
    const float alpha = 1.6732632423543772f;
    return x > 0.f ? scale * x : scale * alpha * (__expf(x) - 1.f);
}

// quad_perm DPP helpers (pairs stay inside quads)
static __device__ __forceinline__ int pb0(int v) {   // lanes {0,1}<-0, {2,3}<-2
    return __builtin_amdgcn_mov_dpp(v, 0xA0, 0xf, 0xf, true);
}
static __device__ __forceinline__ int pb1(int v) {   // lanes {0,1}<-1, {2,3}<-3
    return __builtin_amdgcn_mov_dpp(v, 0xF5, 0xf, 0xf, true);
}
static __device__ __forceinline__ float pswap(float x) {  // pair swap [1,0,3,2]
    return __int_as_float(__builtin_amdgcn_mov_dpp(__float_as_int(x), 0xB1, 0xf, 0xf, true));
}

static __device__ __forceinline__ void acc_add(__half2& a0, __half2& a1,
                                               __half2& a2, __half2& a3, H2x4 v) {
    a0 = __hadd2(a0, v.x); a1 = __hadd2(a1, v.y);
    a2 = __hadd2(a2, v.z); a3 = __hadd2(a3, v.w);
}

// ============================ CSR build (unchanged) =========================

__global__ void k_hist(const int* __restrict__ dst, int* __restrict__ MT,
                       int e, int nb) {
    __shared__ int hist[NBMAX];
    for (int t = threadIdx.x; t < nb; t += 256) hist[t] = 0;
    __syncthreads();
    int chunk = (e + NBLK - 1) / NBLK;
    int lo = blockIdx.x * chunk, hi = min(e, lo + chunk);
    for (int i = lo + threadIdx.x; i < hi; i += 256)
        atomicAdd(&hist[dst[i] >> 8], 1);
    __syncthreads();
    for (int t = threadIdx.x; t < nb; t += 256)
        MT[t * NBLK + blockIdx.x] = hist[t];
}

__global__ void k_cscan(int* __restrict__ MT, int* __restrict__ tot, int nb) {
    int k = blockIdx.x;
    int lane = threadIdx.x;  // 64
    int carry = 0;
    #pragma unroll
    for (int r = 0; r < NBLK; r += 64) {
        int v = MT[k * NBLK + r + lane];
        int inc = v;
        #pragma unroll
        for (int d = 1; d < 64; d <<= 1) {
            int w = __shfl_up(inc, d, 64);
            if (lane >= d) inc += w;
        }
        MT[k * NBLK + r + lane] = carry + inc - v;
        carry += __shfl(inc, 63, 64);
    }
    if (lane == 0) tot[k] = carry;
}

__global__ void k_bscan(const int* __restrict__ tot, int* __restrict__ base,
                        int* __restrict__ rp, int nb, int e, int n) {
    __shared__ int s[512];
    int t = threadIdx.x;
    int v = (t < nb) ? tot[t] : 0;
    s[t] = v;
    __syncthreads();
    #pragma unroll
    for (int d = 1; d < 512; d <<= 1) {
        int w = (t >= d) ? s[t - d] : 0;
        __syncthreads();
        s[t] += w;
        __syncthreads();
    }
    if (t < nb) base[t] = s[t] - v;
    if (t == nb - 1) base[nb] = s[t];
    if (t == 0) rp[n] = e;
}

__global__ void k_scatter(const int* __restrict__ src, const int* __restrict__ dst,
                          const int* __restrict__ MT, const int* __restrict__ base,
                          uint_t* __restrict__ pairs, int e, int nb) {
    __shared__ int cur[NBMAX];
    for (int t = threadIdx.x; t < nb; t += 256)
        cur[t] = base[t] + MT[t * NBLK + blockIdx.x];
    __syncthreads();
    int chunk = (e + NBLK - 1) / NBLK;
    int lo = blockIdx.x * chunk, hi = min(e, lo + chunk);
    for (int i = lo + threadIdx.x; i < hi; i += 256) {
        int d = dst[i];
        int pos = atomicAdd(&cur[d >> 8], 1);
        pairs[pos] = (uint_t)src[i] | ((uint_t)(d & 255) << 24);
    }
}

__global__ void k_build(const uint_t* __restrict__ pairs, const int* __restrict__ base,
                        int* __restrict__ rp, int* __restrict__ esrc, int n) {
    int k = blockIdx.x;
    int bb = base[k], be = base[k + 1];
    __shared__ int cnt[256], cur[256], stmp[256];
    int t = threadIdx.x;
    cnt[t] = 0;
    __syncthreads();
    for (int i = bb + t; i < be; i += 256)
        atomicAdd(&cnt[pairs[i] >> 24], 1);
    __syncthreads();
    int v = cnt[t];
    stmp[t] = v;
    __syncthreads();
    #pragma unroll
    for (int d = 1; d < 256; d <<= 1) {
        int w = (t >= d) ? stmp[t - d] : 0;
        __syncthreads();
        stmp[t] += w;
        __syncthreads();
    }
    int excl = stmp[t] - v;
    int nd = k * 256 + t;
    if (nd < n) rp[nd] = bb + excl;
    cur[t] = bb + excl;
    __syncthreads();
    for (int i = bb + t; i < be; i += 256) {
        uint_t p = pairs[i];
        int pos = atomicAdd(&cur[p >> 24], 1);
        esrc[pos] = (int)(p & 0xFFFFFFu);
    }
}

// ============================ network kernels ===============================

// block 0: agg(x) + MLP[1,16,32] -> h1 AND g1 = h1 @ W1next. One thread/node.
__global__ void k_b0g(const float* __restrict__ x, const int* __restrict__ rp,
                      const int* __restrict__ esrc,
                      const float* __restrict__ W1, const float* __restrict__ b1,
                      const float* __restrict__ W2, const float* __restrict__ b2,
                      const float* __restrict__ W1next,
                      __half2* __restrict__ hout, __half2* __restrict__ gout, int n) {
    __shared__ float sW1[16], sb1[16], sW2[512], sb2[32], sWn[512];
    if (threadIdx.x < 16) { sW1[threadIdx.x] = W1[threadIdx.x]; sb1[threadIdx.x] = b1[threadIdx.x]; }
    for (int t = threadIdx.x; t < 512; t += 256) { sW2[t] = W2[t]; sWn[t] = W1next[t]; }
    if (threadIdx.x < 32) sb2[threadIdx.x] = b2[threadIdx.x];
    __syncthreads();
    int i = blockIdx.x * blockDim.x + threadIdx.x;
    if (i >= n) return;
    float a = x[i];
    int b = rp[i], en = rp[i + 1];
    int j = b;
    for (; j + 4 <= en; j += 4) {
        int s0 = esrc[j], s1 = esrc[j + 1], s2 = esrc[j + 2], s3 = esrc[j + 3];
        float x0 = x[s0], x1 = x[s1], x2 = x[s2], x3 = x[s3];
        a += (x0 + x1) + (x2 + x3);
    }
    for (; j < en; ++j) a += x[esrc[j]];
    float u[16];
    #pragma unroll
    for (int k = 0; k < 16; ++k) u[k] = selu_f(fmaf(a, sW1[k], sb1[k]));
    float row[32];
    #pragma unroll
    for (int jj = 0; jj < 32; ++jj) {
        float acc = sb2[jj];
        #pragma unroll
        for (int k = 0; k < 16; ++k) acc = fmaf(u[k], sW2[k * 32 + jj], acc);
        row[jj] = acc;
    }
    H2x4* op = (H2x4*)hout + (size_t)i * 4;
    #pragma unroll
    for (int q = 0; q < 4; ++q) {
        H2x4 vv;
        vv.x = __floats2half2_rn(row[q * 8 + 0], row[q * 8 + 1]);
        vv.y = __floats2half2_rn(row[q * 8 + 2], row[q * 8 + 3]);
        vv.z = __floats2half2_rn(row[q * 8 + 4], row[q * 8 + 5]);
        vv.w = __floats2half2_rn(row[q * 8 + 6], row[q * 8 + 7]);
        op[q] = vv;
    }
    // fused projection g1 = row @ W1next
    float g[16];
    #pragma unroll
    for (int k = 0; k < 16; ++k) g[k] = 0.f;
    #pragma unroll
    for (int c = 0; c < 32; ++c) {
        float vc = row[c];
        #pragma unroll
        for (int k = 0; k < 16; ++k) g[k] = fmaf(vc, sWn[c * 16 + k], g[k]);
    }
    H2x4* gp = (H2x4*)gout + (size_t)i * 2;
    #pragma unroll
    for (int q = 0; q < 2; ++q) {
        H2x4 vv;
        vv.x = __floats2half2_rn(g[q * 8 + 0], g[q * 8 + 1]);
        vv.y = __floats2half2_rn(g[q * 8 + 2], g[q * 8 + 3]);
        vv.z = __floats2half2_rn(g[q * 8 + 4], g[q * 8 + 5]);
        vv.w = __floats2half2_rn(g[q * 8 + 6], g[q * 8 + 7]);
        gp[q] = vv;
    }
}

// mid gather + MLP + residual + fused next-projection.
// MODE 0: write h_{i+1} and g_{i+1} = h_{i+1} @ W1next.
// MODE 1: write z = h_{i+1} @ Wlast (only z feeds the final gather).
template<int MODE>
__global__ __launch_bounds__(256, 4) void k_gmid(
    const __half2* __restrict__ gin, const __half2* __restrict__ hin,
    const int* __restrict__ rp, const int* __restrict__ esrc,
    const float* __restrict__ W2, const float* __restrict__ b1,
    const float* __restrict__ b2, const float* __restrict__ Wnext,
    __half2* __restrict__ hout, __half2* __restrict__ gout,
    float* __restrict__ zout, int n) {
    __shared__ float sW2[512], sb1[16], sb2[32];
    __shared__ float sWn[512];   // MODE 0: W1next [32][16]; MODE 1: first 32 = Wlast
    for (int t = threadIdx.x; t < 512; t += 256) sW2[t] = W2[t];
    if (MODE == 0) {
        for (int t = threadIdx.x; t < 512; t += 256) sWn[t] = Wnext[t];
    } else {
        if (threadIdx.x < 32) sWn[threadIdx.x] = Wnext[threadIdx.x];
    }
    if (threadIdx.x < 16) sb1[threadIdx.x] = b1[threadIdx.x];
    else if (threadIdx.x < 48) sb2[threadIdx.x - 16] = b2[threadIdx.x - 16];
    __syncthreads();

    const int lane2 = threadIdx.x & 1;
    const int node = blockIdx.x * 128 + (threadIdx.x >> 1);
    if (node >= n) return;

    const H2x4* grows = (const H2x4*)gin;
    H2x4 a = grows[(size_t)node * 2 + lane2];
    __half2 a0 = a.x, a1 = a.y, a2 = a.z, a3 = a.w;

    int b = rp[node];
    int deg = rp[node + 1] - b;
    int j0 = 0;
    for (; j0 + 8 <= deg; j0 += 8) {
        int e0 = esrc[b + j0 + lane2];
        int e1 = esrc[b + j0 + 2 + lane2];
        int e2 = esrc[b + j0 + 4 + lane2];
        int e3 = esrc[b + j0 + 6 + lane2];
        int s0 = pb0(e0), s1 = pb1(e0), s2 = pb0(e1), s3 = pb1(e1);
        int s4 = pb0(e2), s5 = pb1(e2), s6 = pb0(e3), s7 = pb1(e3);
        H2x4 v0 = grows[(size_t)s0 * 2 + lane2];
        H2x4 v1 = grows[(size_t)s1 * 2 + lane2];
        H2x4 v2 = grows[(size_t)s2 * 2 + lane2];
        H2x4 v3 = grows[(size_t)s3 * 2 + lane2];
        H2x4 v4 = grows[(size_t)s4 * 2 + lane2];
        H2x4 v5 = grows[(size_t)s5 * 2 + lane2];
        H2x4 v6 = grows[(size_t)s6 * 2 + lane2];
        H2x4 v7 = grows[(size_t)s7 * 2 + lane2];
        acc_add(a0, a1, a2, a3, v0);
        acc_add(a0, a1, a2, a3, v1);
        acc_add(a0, a1, a2, a3, v2);
        acc_add(a0, a1, a2, a3, v3);
        acc_add(a0, a1, a2, a3, v4);
        acc_add(a0, a1, a2, a3, v5);
        acc_add(a0, a1, a2, a3, v6);
        acc_add(a0, a1, a2, a3, v7);
    }
    for (; j0 < deg; ++j0) {
        int s = esrc[b + j0];
        H2x4 v = grows[(size_t)s * 2 + lane2];
        acc_add(a0, a1, a2, a3, v);
    }

    float2 f0 = __half22float2(a0), f1 = __half22float2(a1),
           f2 = __half22float2(a2), f3 = __half22float2(a3);
    float u[8] = {f0.x, f0.y, f1.x, f1.y, f2.x, f2.y, f3.x, f3.y};
    const int kb = lane2 * 8;
    #pragma unroll
    for (int q = 0; q < 8; ++q) u[q] = selu_f(u[q] + sb1[kb + q]);

    float ua[16];
    #pragma unroll
    for (int q = 0; q < 8; ++q) {
        float uo = pswap(u[q]);
        ua[q]     = lane2 ? uo   : u[q];
        ua[8 + q] = lane2 ? u[q] : uo;
    }

    const H2x4* hrows = (const H2x4*)hin;
    H2x4 h0 = hrows[(size_t)node * 4 + lane2 * 2];
    H2x4 h1 = hrows[(size_t)node * 4 + lane2 * 2 + 1];
    float hv[16];
    {
        float2 g0 = __half22float2(h0.x), g1 = __half22float2(h0.y),
               g2 = __half22float2(h0.z), g3 = __half22float2(h0.w);
        float2 g4 = __half22float2(h1.x), g5 = __half22float2(h1.y),
               g6 = __half22float2(h1.z), g7 = __half22float2(h1.w);
        hv[0] = g0.x; hv[1] = g0.y; hv[2] = g1.x; hv[3] = g1.y;
        hv[4] = g2.x; hv[5] = g2.y; hv[6] = g3.x; hv[7] = g3.y;
        hv[8] = g4.x; hv[9] = g4.y; hv[10] = g5.x; hv[11] = g5.y;
        hv[12] = g6.x; hv[13] = g6.y; hv[14] = g7.x; hv[15] = g7.y;
    }

    const int jb = lane2 * 16;
    float o[16];
    #pragma unroll
    for (int q = 0; q < 16; ++q) {
        float oo = sb2[jb + q];
        #pragma unroll
        for (int k = 0; k < 16; ++k) oo = fmaf(ua[k], sW2[k * 32 + jb + q], oo);
        o[q] = oo + hv[q];
    }

    if (MODE == 0) {
        H2x4 o0, o1;
        o0.x = __floats2half2_rn(o[0], o[1]);   o0.y = __floats2half2_rn(o[2], o[3]);
        o0.z = __floats2half2_rn(o[4], o[5]);   o0.w = __floats2half2_rn(o[6], o[7]);
        o1.x = __floats2half2_rn(o[8], o[9]);   o1.y = __floats2half2_rn(o[10], o[11]);
        o1.z = __floats2half2_rn(o[12], o[13]); o1.w = __floats2half2_rn(o[14], o[15]);
        ((H2x4*)hout)[(size_t)node * 4 + lane2 * 2]     = o0;
        ((H2x4*)hout)[(size_t)node * 4 + lane2 * 2 + 1] = o1;
        // fused projection: g_next = h_next @ W1next; this lane owns channels
        // jb..jb+15; partial over those, then pair-sum via DPP.
        float gp[16];
        #pragma unroll
        for (int k = 0; k < 16; ++k) gp[k] = 0.f;
        #pragma unroll
        for (int q = 0; q < 16; ++q) {
            float vc = o[q];
            #pragma unroll
            for (int k = 0; k < 16; ++k)
                gp[k] = fmaf(vc, sWn[(jb + q) * 16 + k], gp[k]);
        }
        #pragma unroll
        for (int k = 0; k < 16; ++k) gp[k] += pswap(gp[k]);
        // lane writes its 8 g channels (kb..kb+7)
        H2x4 gv;
        gv.x = __floats2half2_rn(gp[kb + 0], gp[kb + 1]);
        gv.y = __floats2half2_rn(gp[kb + 2], gp[kb + 3]);
        gv.z = __floats2half2_rn(gp[kb + 4], gp[kb + 5]);
        gv.w = __floats2half2_rn(gp[kb + 6], gp[kb + 7]);
        ((H2x4*)gout)[(size_t)node * 2 + lane2] = gv;
    } else {
        // z = o . Wlast[jb..jb+15], pair-sum
        float zp = 0.f;
        #pragma unroll
        for (int q = 0; q < 16; ++q) zp = fmaf(o[q], sWn[jb + q], zp);
        zp += pswap(zp);
        if (lane2 == 0) zout[node] = zp;
    }
}

// last gather: out = z + sum z[src], one thread per node
__global__ void k_gz(const float* __restrict__ z, const int* __restrict__ rp,
                     const int* __restrict__ esrc, float* __restrict__ out, int n) {
    int i = blockIdx.x * blockDim.x + threadIdx.x;
    if (i >= n) return;
    float acc = z[i];
    int b = rp[i], en = rp[i + 1];
    int j = b;
    for (; j + 4 <= en; j += 4) {
        int s0 = esrc[j], s1 = esrc[j + 1], s2 = esrc[j + 2], s3 = esrc[j + 3];
        float z0 = z[s0], z1 = z[s1], z2 = z[s2], z3 = z[s3];
        acc += (z0 + z1) + (z2 + z3);
    }
    for (; j < en; ++j) acc += z[esrc[j]];
    out[i] = acc;
}

// ---------------------------------------------------------------------------

extern "C" void kernel_launch(void* const* d_in, const int* in_sizes, int n_in,
                              void* d_out, int out_size, void* d_ws, size_t ws_size,
                              hipStream_t stream) {
    const float* x    = (const float*)d_in[0];
    const int*   ei   = (const int*)d_in[1];
    const float* W1_0 = (const float*)d_in[2];
    const float* b1_0 = (const float*)d_in[3];
    const float* W2_0 = (const float*)d_in[4];
    const float* b2_0 = (const float*)d_in[5];
    const float* W1m  = (const float*)d_in[6];
    const float* b1m  = (const float*)d_in[7];
    const float* W2m  = (const float*)d_in[8];
    const float* b2m  = (const float*)d_in[9];
    const float* Wl   = (const float*)d_in[10];

    const int n = in_sizes[0];      // 100000 nodes
    const int e = in_sizes[1] / 2;  // 1.6M edges
    const int* src  = ei;
    const int* dstp = ei + e;
    const int nb = (n + 255) >> 8;

    char* ws = (char*)d_ws;
    size_t off = 0;
    auto alloc = [&](size_t bytes) -> char* {
        char* p = ws + off;
        off += (bytes + 255) & ~size_t(255);
        return p;
    };
    __half2* hP   = (__half2*)alloc((size_t)n * 32 * 2);
    __half2* hQ   = (__half2*)alloc((size_t)n * 32 * 2);
    __half2* gA   = (__half2*)alloc((size_t)n * 16 * 2);
    __half2* gB   = (__half2*)alloc((size_t)n * 16 * 2);
    float*   z    = (float*)alloc((size_t)n * 4);
    int*     rp   = (int*)alloc((size_t)(n + 1) * 4);
    int*     esrc = (int*)alloc((size_t)e * 4);
    uint_t*  pairs= (uint_t*)alloc((size_t)e * 4);
    int*     MT   = (int*)alloc((size_t)NBMAX * NBLK * 4);
    int*     base = (int*)alloc((size_t)(NBMAX + 1) * 4);
    int*     tot  = (int*)alloc((size_t)NBMAX * 4);
    (void)ws_size;

    const int B = 256;
    const int gN = (n + B - 1) / B;
    const int gG = (n + 127) / 128;

    // --- CSR build ---
    k_hist<<<NBLK, B, 0, stream>>>(dstp, MT, e, nb);
    k_cscan<<<nb, 64, 0, stream>>>(MT, tot, nb);
    k_bscan<<<1, 512, 0, stream>>>(tot, base, rp, nb, e, n);
    k_scatter<<<NBLK, B, 0, stream>>>(src, dstp, MT, base, pairs, e, nb);
    k_build<<<nb, B, 0, stream>>>(pairs, base, rp, esrc, n);

    // --- block 0 (+ fused g1) ---
    k_b0g<<<gN, B, 0, stream>>>(x, rp, esrc, W1_0, b1_0, W2_0, b2_0,
                                W1m /* W1[0] */, hP, gA, n);

    // --- blocks 1..8, projection fused into epilogue ---
    __half2* A = hP;  __half2* Bf = hQ;
    __half2* gin = gA; __half2* gnx = gB;
    for (int i = 0; i < 8; ++i) {
        if (i < 7) {
            k_gmid<0><<<gG, B, 0, stream>>>(gin, A, rp, esrc, W2m + i * 512,
                                            b1m + i * 16, b2m + i * 32,
                                            W1m + (i + 1) * 512,
                                            Bf, gnx, nullptr, n);
        } else {
            k_gmid<1><<<gG, B, 0, stream>>>(gin, A, rp, esrc, W2m + i * 512,
                                            b1m + i * 16, b2m + i * 32,
                                            Wl, Bf, nullptr, z, n);
        }
        __half2* t = A; A = Bf; Bf = t;
        __half2* tg = gin; gin = gnx; gnx = tg;
    }

    // --- block 9: gather of z ---
    k_gz<<<gN, B, 0, stream>>>(z, rp, esrc, (float*)d_out, n);
}